// Round 9
// baseline (781.217 us; speedup 1.0000x reference)
//
#include <hip/hip_runtime.h>
#include <math.h>

#define NPROP 512
#define NB 2
#define NROWS (NB*NPROP)          // 1024
#define FCH 256
#define FH 64
#define FW 64
#define INDIM (FCH*7*7)           // 12544
#define HID 1024
#define NCLS 81
#define CAND_PER_IMG (NPROP*(NCLS-1))  // 40960
#define CLIPV 4.1351666f          // log(1000/16) rounded to f32

typedef _Float16 f16x8 __attribute__((ext_vector_type(8)));
typedef float f32x4 __attribute__((ext_vector_type(4)));
typedef unsigned int u32;
typedef unsigned long long u64;

__device__ __forceinline__ void gload16(const void* g, void* l) {
    __builtin_amdgcn_global_load_lds((const __attribute__((address_space(1))) u32*)g,
                                     (__attribute__((address_space(3))) u32*)l, 16, 0, 0);
}

// Limb planes are k-octet-major: [K/8][1024][8] f16. Octet stride = 8192 elems.
// -> staging gload16 reads 64 consecutive 16B chunks (coalesced 1KB/instr).

// ---- workspace layout (bytes) ----
#define XHI_OFF    0ull
#define XLO_OFF    25690112ull
#define WT1HI_OFF  51380224ull
#define WT1LO_OFF  77070336ull
#define WT2HI_OFF  102760448ull
#define WT2LO_OFF  104857600ull
#define H1HI_OFF   106954752ull
#define H1LO_OFF   109051904ull
#define H2_OFF     111149056ull
#define CWT_OFF    115343360ull
#define BWT_OFF    116338688ull
#define PROBS_OFF  116387840ull
#define CUR_OFF    116719616ull
#define CNT_OFF    116736000ull   // ccnt[160] ints
#define CCS_OFF    116737024ull   // per-class scores   [160][512] f32
#define CCOB_OFF   117064704ull   // per-class off-box  [160][512] float4
#define CCAR_OFF   118375424ull   // per-class area     [160][512] f32
#define CCBX_OFF   118703104ull   // per-class box      [160][512] float4
#define CCIX_OFF   120013824ull   // per-class coidx    [160][512] int
#define SVS_OFF    120341504ull   // survivors score    [160][128] f32
#define SVB_OFF    120423424ull   // survivors box      [160][128] float4
#define SVI_OFF    120751104ull   // survivors coidx    [160][128] int
#define SVC_OFF    120833024ull   // survivor count     [160] int
#define PART_OFF   121489408ull   // 16 planes of 1024x1024 f32 = 67 MB

__global__ void init_kernel(int* ccnt) {
    if (threadIdx.x < 160) ccnt[threadIdx.x] = 0;
}

// one block per (b,n) proposal; writes scaled f16 limb planes of X
// (k-octet-major: X[(i>>3)*8192 + r*8 + (i&7)])
__global__ __launch_bounds__(256) void roi_align_kernel(
    const float* __restrict__ feat, const float* __restrict__ boxes,
    _Float16* __restrict__ Xhi, _Float16* __restrict__ Xlo)
{
    int r = blockIdx.x;           // b*512+n
    int b = r >> 9;
    const float* f = feat + (size_t)b * (FCH*FH*FW);
    __shared__ float sb[4];
    __shared__ int   sx0[49], sx1[49], sy0[49], sy1[49];
    __shared__ float sw00[49], sw01[49], sw10[49], sw11[49];
    int tid = threadIdx.x;
    if (tid == 0) {
        float x1 = boxes[r*4+0]*0.125f, y1 = boxes[r*4+1]*0.125f;
        float x2 = boxes[r*4+2]*0.125f, y2 = boxes[r*4+3]*0.125f;
        sb[0] = x1; sb[1] = y1;
        sb[2] = fmaxf(x2-x1, 1.0f) / 7.0f;   // bw
        sb[3] = fmaxf(y2-y1, 1.0f) / 7.0f;   // bh
    }
    __syncthreads();
    if (tid < 49) {
        int py = tid / 7, px = tid - py*7;
        float gx = sb[0] + ((float)px + 0.5f)*sb[2];
        float gy = sb[1] + ((float)py + 0.5f)*sb[3];
        gx = fminf(fmaxf(gx, 0.0f), 63.0f);
        gy = fminf(fmaxf(gy, 0.0f), 63.0f);
        float x0f = floorf(gx), y0f = floorf(gy);
        int x0 = (int)x0f, y0 = (int)y0f;
        sx0[tid] = x0; sy0[tid] = y0;
        sx1[tid] = min(x0+1, 63); sy1[tid] = min(y0+1, 63);
        float dx = gx - x0f, dy = gy - y0f;
        sw00[tid] = (1.0f-dy)*(1.0f-dx);
        sw01[tid] = (1.0f-dy)*dx;
        sw10[tid] = dy*(1.0f-dx);
        sw11[tid] = dy*dx;
    }
    __syncthreads();
    for (int i = tid; i < INDIM; i += 256) {
        int c = i / 49;
        int p = i - c*49;
        const float* fc = f + c*(FH*FW);
        int r0 = sy0[p]*FW, r1 = sy1[p]*FW;
        float v = fc[r0 + sx0[p]]*sw00[p] + fc[r0 + sx1[p]]*sw01[p]
                + fc[r1 + sx0[p]]*sw10[p] + fc[r1 + sx1[p]]*sw11[p];
        float vs = v * 32.0f;
        _Float16 h = (_Float16)vs;
        size_t idx = ((size_t)(i >> 3) << 13) + ((size_t)r << 3) + (i & 7);
        Xhi[idx] = h;
        Xlo[idx] = (_Float16)(vs - (float)h);
    }
}

// in [K][N] fp32 -> hi/lo k-octet-major [(K/8)][N][8] f16 (scaled). N=1024.
__global__ __launch_bounds__(256) void trans_limb(
    const float* __restrict__ in, _Float16* __restrict__ hi, _Float16* __restrict__ lo,
    int K, int N, float scale)
{
    __shared__ float t[32][33];
    int tx = threadIdx.x & 31, ty = threadIdx.x >> 5;   // ty 0..7
    int n0 = blockIdx.x << 5, k0 = blockIdx.y << 5;
#pragma unroll
    for (int r = 0; r < 4; ++r)
        t[ty + 8*r][tx] = in[(size_t)(k0 + ty + 8*r)*N + n0 + tx];
    __syncthreads();
#pragma unroll
    for (int r = 0; r < 4; ++r) {
        int n = n0 + ty + 8*r, k = k0 + tx;
        float v = t[tx][ty + 8*r] * scale;
        _Float16 h = (_Float16)v;
        size_t idx = ((size_t)(k >> 3)*N << 3) + ((size_t)n << 3) + (k & 7);
        hi[idx] = h;
        lo[idx] = (_Float16)(v - (float)h);
    }
}

// batched plain transpose: in [b][K][N] -> out [b][N][K] (fp32, small)
__global__ __launch_bounds__(256) void trans_naive(
    const float* __restrict__ in, float* __restrict__ out, int K, int N, int batch)
{
    int idx = blockIdx.x*256 + threadIdx.x;
    int per = K*N;
    if (idx >= per*batch) return;
    int b = idx / per;
    int rem = idx - b*per;
    int n = rem / K, k = rem - n*K;
    out[idx] = in[(size_t)b*per + (size_t)k*N + n];
}

// ---------------------------------------------------------------------------
// fc1 GEMM: 256x256 tile, 8 waves (2x4), f16-limb MFMA, 128KB dynamic-LDS
// double buffer, counted vmcnt(8). Staging now COALESCED via k-octet-major
// planes: each gload16 streams 1KB contiguous (was 64 scattered lines in r8).
// Grid = 16 z * 16 tiles = 256 blocks = 1/CU; z XCD-affine.
// ---------------------------------------------------------------------------
__global__ __launch_bounds__(512, 2) void mfma_gemm_limb256(
    const _Float16* __restrict__ Ahi, const _Float16* __restrict__ Alo,
    const _Float16* __restrict__ Bhi, const _Float16* __restrict__ Blo,
    float* __restrict__ part, int base, int extra)
{
    extern __shared__ __align__(16) char ldsraw[];   // 131072 bytes
    const int tid = threadIdx.x;
    const int lane = tid & 63;
    const int w = tid >> 6;            // 0..7
    const int wm = w >> 2, wn = w & 3; // wave tile: rows wm*128, cols wn*64
    const int kg = lane >> 4, lr = lane & 15;
    const int bid = blockIdx.x;
    const int z = bid & 15;
    const int tile = bid >> 4;
    const int bx = tile & 3, by = tile >> 2;
    const int row0 = by << 8, col0 = bx << 8;
    const int zsteps = base + (z < extra ? 1 : 0);
    const int o0 = ((z*base + (z < extra ? z : extra)) * 32) >> 3;  // start octet

    // staging: wave w owns plane w>>1 (0=Ah 1=Al 2=Bh 3=Bl), half (w&1)
    const int sp = w >> 1;
    const int sbase = (w & 1) * 8;
    const _Float16* pl = (sp == 0) ? Ahi : (sp == 1) ? Alo : (sp == 2) ? Bhi : Blo;
    const int rc0 = (sp < 2) ? row0 : col0;
    const _Float16* sG = pl + ((size_t)(rc0 + lane) << 3);   // per-lane, coalesced

    f32x4 acc[8][4];
#pragma unroll
    for (int i = 0; i < 8; ++i)
#pragma unroll
        for (int j = 0; j < 4; ++j) acc[i][j] = (f32x4){0.f, 0.f, 0.f, 0.f};

    auto STAGE = [&](int bufoff, int koct) {
#pragma unroll
        for (int j = 0; j < 8; ++j) {
            int sub = sbase + j;           // 0..15: ks = sub>>2, rblk = sub&3
            int ks = sub >> 2, rblk = sub & 3;
            const void* g = (const void*)(sG + ((size_t)(o0 + koct + ks) << 13)
                                             + ((size_t)rblk << 9));
            void* l = (void*)(ldsraw + bufoff + sp*16384 + ks*4096 + rblk*1024);
            gload16(g, l);                 // dest uniform; HW adds lane*16
        }
    };

    STAGE(0, 0);
    if (zsteps > 1) STAGE(65536, 4);

    for (int t = 0; t < zsteps; ++t) {
        if (t + 1 < zsteps) asm volatile("s_waitcnt vmcnt(8)" ::: "memory");
        else                asm volatile("s_waitcnt vmcnt(0)" ::: "memory");
        __builtin_amdgcn_s_barrier();          // all waves' stage of tile t done
        asm volatile("" ::: "memory");         // pin reads below barrier
        const char* Lb = ldsraw + ((t & 1) ? 65536 : 0);
        f16x8 Bh[4], Bl[4];
#pragma unroll
        for (int ni = 0; ni < 4; ++ni) {
            int s = (kg*256 + wn*64 + ni*16 + lr) * 16;
            Bh[ni] = *(const f16x8*)(Lb + 2*16384 + s);
            Bl[ni] = *(const f16x8*)(Lb + 3*16384 + s);
        }
#pragma unroll
        for (int mi = 0; mi < 8; ++mi) {       // A reads fused under MFMA
            int s = (kg*256 + wm*128 + mi*16 + lr) * 16;
            f16x8 ah = *(const f16x8*)(Lb + s);
            f16x8 al = *(const f16x8*)(Lb + 16384 + s);
#pragma unroll
            for (int ni = 0; ni < 4; ++ni) {
                acc[mi][ni] = __builtin_amdgcn_mfma_f32_16x16x32_f16(ah, Bh[ni], acc[mi][ni], 0, 0, 0);
                acc[mi][ni] = __builtin_amdgcn_mfma_f32_16x16x32_f16(ah, Bl[ni], acc[mi][ni], 0, 0, 0);
                acc[mi][ni] = __builtin_amdgcn_mfma_f32_16x16x32_f16(al, Bh[ni], acc[mi][ni], 0, 0, 0);
            }
        }
        asm volatile("" ::: "memory");         // pin reads above barrier
        __builtin_amdgcn_s_barrier();          // all waves done reading buf
        asm volatile("" ::: "memory");         // pin STAGE below barrier
        if (t + 2 < zsteps) STAGE((t & 1) ? 65536 : 0, (t+2)*4);
    }

    // epilogue: C/D layout col=lane&15, row=(lane>>4)*4+j
    float* cb = part + ((size_t)z << 20)
              + (size_t)row0*HID + col0 + wn*64 + lr;
#pragma unroll
    for (int mi = 0; mi < 8; ++mi) {
#pragma unroll
        for (int j = 0; j < 4; ++j) {
            int row = wm*128 + mi*16 + kg*4 + j;
            float* pr = cb + (size_t)row*HID;
            pr[0]  = acc[mi][0][j];
            pr[16] = acc[mi][1][j];
            pr[32] = acc[mi][2][j];
            pr[48] = acc[mi][3][j];
        }
    }
}

// ---------------------------------------------------------------------------
// fc2 GEMM: 128x128 tile, depth-2 dbuf, counted vmcnt; coalesced staging.
// ---------------------------------------------------------------------------
__global__ __launch_bounds__(256) void mfma_gemm_limb(
    const _Float16* __restrict__ Ahi, const _Float16* __restrict__ Alo,
    const _Float16* __restrict__ Bhi, const _Float16* __restrict__ Blo,
    float* __restrict__ part, int base, int extra, int lognz)
{
    __shared__ __align__(16) _Float16 lds[2][4][512][8];   // 2 x 32KB
    const int tid = threadIdx.x;
    const int lane = tid & 63;
    const int w = tid >> 6, wm = w >> 1, wn = w & 1;
    const int kg = lane >> 4, lr = lane & 15;
    const int bid = blockIdx.x;
    const int nzm = (1 << lognz) - 1;
    const int z = bid & nzm;
    const int bx = (bid >> lognz) & 7;
    const int by = bid >> (lognz + 3);
    const int row0 = by << 7, col0 = bx << 7;
    const int zsteps = base + (z < extra ? 1 : 0);
    const int o0 = ((z*base + (z < extra ? z : extra)) * 32) >> 3;
    const int r_ = tid & 127;
    const int ks1 = tid >> 7;          // 0 or 1
    const int wb = tid & 192;          // wave-uniform slot base

    const _Float16* srcA0 = Ahi + ((size_t)(row0 + r_) << 3);
    const _Float16* srcA1 = Alo + ((size_t)(row0 + r_) << 3);
    const _Float16* srcB0 = Bhi + ((size_t)(col0 + r_) << 3);
    const _Float16* srcB1 = Blo + ((size_t)(col0 + r_) << 3);

    f32x4 acc[4][4];
#pragma unroll
    for (int i = 0; i < 4; ++i)
#pragma unroll
        for (int j = 0; j < 4; ++j) acc[i][j] = (f32x4){0.f, 0.f, 0.f, 0.f};

#define STAGE(bf, oct) do { \
    _Float16* Lb = &lds[bf][0][0][0]; \
    gload16(srcA0 + ((size_t)(o0+(oct)+ks1  ) << 13), (void*)(Lb + (0*512 +       wb)*8)); \
    gload16(srcA0 + ((size_t)(o0+(oct)+ks1+2) << 13), (void*)(Lb + (0*512 + 256 + wb)*8)); \
    gload16(srcA1 + ((size_t)(o0+(oct)+ks1  ) << 13), (void*)(Lb + (1*512 +       wb)*8)); \
    gload16(srcA1 + ((size_t)(o0+(oct)+ks1+2) << 13), (void*)(Lb + (1*512 + 256 + wb)*8)); \
    gload16(srcB0 + ((size_t)(o0+(oct)+ks1  ) << 13), (void*)(Lb + (2*512 +       wb)*8)); \
    gload16(srcB0 + ((size_t)(o0+(oct)+ks1+2) << 13), (void*)(Lb + (2*512 + 256 + wb)*8)); \
    gload16(srcB1 + ((size_t)(o0+(oct)+ks1  ) << 13), (void*)(Lb + (3*512 +       wb)*8)); \
    gload16(srcB1 + ((size_t)(o0+(oct)+ks1+2) << 13), (void*)(Lb + (3*512 + 256 + wb)*8)); \
} while (0)

    STAGE(0, 0);
    if (1 < zsteps) STAGE(1, 4);
    for (int t = 0; t < zsteps; ++t) {
        if (t + 1 < zsteps) asm volatile("s_waitcnt vmcnt(8)" ::: "memory");
        else                asm volatile("s_waitcnt vmcnt(0)" ::: "memory");
        __builtin_amdgcn_s_barrier();
        const _Float16* Lr = &lds[t & 1][0][0][0];
        f16x8 Ah[4], Al[4], Bh[4], Bl[4];
#pragma unroll
        for (int mi = 0; mi < 4; ++mi) {
            int s = kg*128 + wm*64 + mi*16 + lr;
            Ah[mi] = *(const f16x8*)(Lr + (0*512 + s)*8);
            Al[mi] = *(const f16x8*)(Lr + (1*512 + s)*8);
        }
#pragma unroll
        for (int ni = 0; ni < 4; ++ni) {
            int s = kg*128 + wn*64 + ni*16 + lr;
            Bh[ni] = *(const f16x8*)(Lr + (2*512 + s)*8);
            Bl[ni] = *(const f16x8*)(Lr + (3*512 + s)*8);
        }
        asm volatile("s_waitcnt lgkmcnt(0)" ::: "memory");   // frag data in regs
        __builtin_amdgcn_sched_barrier(0);
        __builtin_amdgcn_s_barrier();                        // all waves done reading
        if (t + 2 < zsteps) STAGE(t & 1, (t+2)*4);           // overwrite just-read buf
#pragma unroll
        for (int mi = 0; mi < 4; ++mi)
#pragma unroll
            for (int ni = 0; ni < 4; ++ni) {
                acc[mi][ni] = __builtin_amdgcn_mfma_f32_16x16x32_f16(Ah[mi], Bh[ni], acc[mi][ni], 0, 0, 0);
                acc[mi][ni] = __builtin_amdgcn_mfma_f32_16x16x32_f16(Ah[mi], Bl[ni], acc[mi][ni], 0, 0, 0);
                acc[mi][ni] = __builtin_amdgcn_mfma_f32_16x16x32_f16(Al[mi], Bh[ni], acc[mi][ni], 0, 0, 0);
            }
    }
#undef STAGE

    // epilogue: C/D layout col=lane&15, row=(lane>>4)*4+j
    float* cb = part + ((size_t)z << 20)
              + (size_t)row0*HID + col0 + wn*64 + lr;
#pragma unroll
    for (int mi = 0; mi < 4; ++mi) {
#pragma unroll
        for (int j = 0; j < 4; ++j) {
            int row = wm*64 + mi*16 + kg*4 + j;
            float* pr = cb + (size_t)row*HID;
            pr[0]  = acc[mi][0][j];
            pr[16] = acc[mi][1][j];
            pr[32] = acc[mi][2][j];
            pr[48] = acc[mi][3][j];
        }
    }
}

// out = relu(sum_p part[p]/2048 + bias); mode 0: fp32 out; mode 1: f16 limb out
// (x32, k-octet-major)
__global__ __launch_bounds__(256) void reduce_bias_relu(
    const float* __restrict__ part, const float* __restrict__ bias,
    float* __restrict__ out32, _Float16* __restrict__ outhi, _Float16* __restrict__ outlo,
    int nsplit, int mode)
{
    int gid = blockIdx.x*256 + threadIdx.x;
    float s = 0.f;
    for (int p = 0; p < nsplit; ++p) s += part[((size_t)p << 20) + gid];
    s = s * (1.0f/2048.0f) + bias[gid & (HID-1)];
    s = fmaxf(s, 0.f);
    if (mode == 0) {
        out32[gid] = s;
    } else {
        float vs = s * 32.0f;
        _Float16 h = (_Float16)vs;
        int row = gid >> 10, col = gid & 1023;
        size_t idx = ((size_t)(col >> 3) << 13) + ((size_t)row << 3) + (col & 7);
        outhi[idx] = h;
        outlo[idx] = (_Float16)(vs - (float)h);
    }
}

// cls+bbox heads + decode (+softmax at last stage). 4 rows per block.
__global__ __launch_bounds__(512) void heads_kernel(
    const float* __restrict__ X, const float* __restrict__ cwT, const float* __restrict__ cb,
    const float* __restrict__ bwT, const float* __restrict__ bbb,
    float* __restrict__ cur, float* __restrict__ probs,
    const int* __restrict__ img_sz, int stage, int write_probs)
{
    __shared__ float xs[4][1024];
    __shared__ float lg[4][96];
    int tid = threadIdx.x;
    int lr = tid >> 7;           // local row 0..3
    int j  = tid & 127;
    int row0 = blockIdx.x * 4;
    for (int i = tid; i < 4096; i += 512)
        xs[i >> 10][i & 1023] = X[(size_t)(row0 + (i >> 10))*1024 + (i & 1023)];
    __syncthreads();
    int row = row0 + lr;
    if (j < 85) {
        const float* wrow = (j < 81) ? (cwT + (size_t)j*HID) : (bwT + (size_t)(j-81)*HID);
        float acc = (j < 81) ? cb[j] : bbb[j-81];
        const float4* w4 = (const float4*)wrow;
#pragma unroll 4
        for (int k4 = 0; k4 < 256; ++k4) {
            float4 wv = w4[k4];
            const float* xr = &xs[lr][k4*4];
            acc = fmaf(xr[0], wv.x, acc);
            acc = fmaf(xr[1], wv.y, acc);
            acc = fmaf(xr[2], wv.z, acc);
            acc = fmaf(xr[3], wv.w, acc);
        }
        lg[lr][j] = acc;
    }
    __syncthreads();
    if (j == 0) {   // box decode + clip
        float img = (float)(*img_sz);
        float px1 = cur[row*4+0], py1 = cur[row*4+1];
        float px2 = cur[row*4+2], py2 = cur[row*4+3];
        float pw = fmaxf(px2-px1, 1e-6f), ph = fmaxf(py2-py1, 1e-6f);
        float pcx = px1 + 0.5f*pw, pcy = py1 + 0.5f*ph;
        float wx, wy, ww, wh;
        if (stage == 0)      { wx=0.1f;   wy=0.1f;   ww=0.2f;   wh=0.2f;   }
        else if (stage == 1) { wx=0.05f;  wy=0.05f;  ww=0.1f;   wh=0.1f;   }
        else                 { wx=0.033f; wy=0.033f; ww=0.067f; wh=0.067f; }
        float dx = lg[lr][81]*wx, dy = lg[lr][82]*wy;
        float dw = fminf(lg[lr][83]*ww, CLIPV);
        float dh = fminf(lg[lr][84]*wh, CLIPV);
        float cx = dx*pw + pcx, cy = dy*ph + pcy;
        float w = expf(dw)*pw, h = expf(dh)*ph;
        cur[row*4+0] = fminf(fmaxf(cx - 0.5f*w, 0.f), img);
        cur[row*4+1] = fminf(fmaxf(cy - 0.5f*h, 0.f), img);
        cur[row*4+2] = fminf(fmaxf(cx + 0.5f*w, 0.f), img);
        cur[row*4+3] = fminf(fmaxf(cy + 0.5f*h, 0.f), img);
    }
    if (write_probs) {
        if (j == 1) {
            float m = lg[lr][0];
            for (int c2 = 1; c2 < 81; ++c2) m = fmaxf(m, lg[lr][c2]);
            float s = 0.f;
            for (int c2 = 0; c2 < 81; ++c2) s += expf(lg[lr][c2] - m);
            lg[lr][88] = m; lg[lr][89] = s;
        }
        __syncthreads();
        if (j < 81)
            probs[(size_t)row*81 + j] = expf(lg[lr][j] - lg[lr][88]) / lg[lr][89];
    }
}

// bucket passing candidates per (image,class); cross-class IoU is exactly 0
// (label offset trick), so NMS decomposes per class.
__global__ __launch_bounds__(256) void compact_class(
    const float* __restrict__ probs, const float* __restrict__ cur,
    const int* __restrict__ img_sz, int* __restrict__ ccnt,
    float* __restrict__ ccs, float4* __restrict__ ccob, float* __restrict__ ccar,
    float4* __restrict__ ccbx, int* __restrict__ ccix)
{
    int gid = blockIdx.x*256 + threadIdx.x;
    if (gid >= NB*CAND_PER_IMG) return;
    int b = gid / CAND_PER_IMG;
    int rem = gid - b*CAND_PER_IMG;
    int n = rem / 80;
    int cm = rem - n*80;
    int label = cm + 1;
    int r = b*NPROP + n;
    float s = probs[(size_t)r*81 + label];
    float b0 = cur[r*4+0], b1 = cur[r*4+1], b2 = cur[r*4+2], b3 = cur[r*4+3];
    if (s > 0.05f && (b2 - b0) >= 1.0f && (b3 - b1) >= 1.0f) {
        int cls = b*80 + cm;
        int pos = atomicAdd(&ccnt[cls], 1);
        int base = cls*512 + pos;
        float img = (float)(*img_sz);
        float t = (float)label * (img + 2.0f);
        float o0 = b0+t, o1 = b1+t, o2 = b2+t, o3 = b3+t;
        ccs[base] = s;
        ccob[base] = make_float4(o0, o1, o2, o3);
        ccar[base] = fmaxf(o2-o0, 0.f) * fmaxf(o3-o1, 0.f);
        ccbx[base] = make_float4(b0, b1, b2, b3);
        ccix[base] = rem;   // reference flat order for tie-break
    }
}

// one wave per (image,class): greedy NMS entirely in registers
__global__ __launch_bounds__(64) void class_nms(
    const int* __restrict__ ccnt, const float* __restrict__ ccs,
    const float4* __restrict__ ccob, const float* __restrict__ ccar,
    const float4* __restrict__ ccbx, const int* __restrict__ ccix,
    float* __restrict__ svs, float4* __restrict__ svb, int* __restrict__ svi,
    int* __restrict__ svc)
{
    int cls = blockIdx.x;          // 0..159
    int Nc = ccnt[cls];
    int base = cls*512;
    int lane = threadIdx.x;
    __shared__ float sel[5];
    float s[8]; float4 ob[8]; float a[8]; int ix[8];
    int cntl = 0;
    for (int j = lane; j < Nc; j += 64) {
        s[cntl] = ccs[base+j]; ob[cntl] = ccob[base+j];
        a[cntl] = ccar[base+j]; ix[cntl] = ccix[base+j];
        ++cntl;
    }
    int svn = 0;
    int rounds = (Nc < 100) ? Nc : 100;
    for (int it = 0; it < rounds; ++it) {
        float bs = -1.f; int bi = 0x7fffffff;
        for (int q = 0; q < cntl; ++q)
            if (s[q] > bs || (s[q] == bs && ix[q] < bi)) { bs = s[q]; bi = ix[q]; }
        for (int off = 32; off > 0; off >>= 1) {
            float os = __shfl_xor(bs, off);
            int oi = __shfl_xor(bi, off);
            if (os > bs || (os == bs && oi < bi)) { bs = os; bi = oi; }
        }
        if (bs <= 0.f) break;      // uniform across wave
        for (int q = 0; q < cntl; ++q) {
            if (s[q] == bs && ix[q] == bi) {   // unique owner (ix unique)
                sel[0] = ob[q].x; sel[1] = ob[q].y; sel[2] = ob[q].z; sel[3] = ob[q].w;
                sel[4] = a[q];
                int slot = cls*128 + svn;
                svs[slot] = bs;
                svb[slot] = ccbx[base + lane + q*64];
                svi[slot] = bi;
                s[q] = -1.f;
            }
        }
        __syncthreads();
        float bi0 = sel[0], bi1 = sel[1], bi2 = sel[2], bi3 = sel[3], ai = sel[4];
        for (int q = 0; q < cntl; ++q) {
            if (s[q] > 0.f) {
                float ix1 = fmaxf(bi0, ob[q].x), iy1 = fmaxf(bi1, ob[q].y);
                float ix2 = fminf(bi2, ob[q].z), iy2 = fminf(bi3, ob[q].w);
                float inter = fmaxf(ix2-ix1, 0.f) * fmaxf(iy2-iy1, 0.f);
                float iou = inter / (ai + a[q] - inter + 1e-9f);
                if (iou > 0.5f) s[q] = -1.f;
            }
        }
        ++svn;
        __syncthreads();
    }
    if (lane == 0) svc[cls] = svn;
}

// per image: bitonic-sort survivors by (score desc, coidx asc), write top-100.
// key = (score_bits << 32) | (~coidx); invalid slots key=0 sort last.
__global__ __launch_bounds__(256) void merge_topk(
    const float* __restrict__ svs, const float4* __restrict__ svb,
    const int* __restrict__ svi, const int* __restrict__ svc,
    float* __restrict__ out)
{
    extern __shared__ char smem[];
    u64* keys = (u64*)smem;                 // [8192] 64KB
    u32* pay  = (u32*)(smem + 65536);       // [8192] 32KB
    __shared__ int off[81];
    __shared__ int n2s;
    int b = blockIdx.x, tid = threadIdx.x;
    if (tid == 0) {
        int run = 0;
        for (int c = 0; c < 80; ++c) { off[c] = run; run += svc[b*80 + c]; }
        off[80] = run;
        int n2 = 256;
        while (n2 < run) n2 <<= 1;
        n2s = n2;
    }
    __syncthreads();
    int Ns = off[80], n2 = n2s;
    for (int c = 0; c < 80; ++c) {
        int n = off[c+1] - off[c];
        int srcb = (b*80 + c)*128;
        for (int k = tid; k < n; k += 256) {
            int src = srcb + k;
            keys[off[c] + k] = ((u64)__float_as_uint(svs[src]) << 32)
                             | (u64)(0xFFFFFFFFu - (u32)svi[src]);
            pay[off[c] + k] = src;
        }
    }
    for (int i = Ns + tid; i < n2; i += 256) { keys[i] = 0; pay[i] = 0; }
    __syncthreads();
    for (int k = 2; k <= n2; k <<= 1) {
        for (int j = k >> 1; j > 0; j >>= 1) {
            for (int i = tid; i < n2; i += 256) {
                int l = i ^ j;
                if (l > i) {
                    u64 a = keys[i], bb = keys[l];
                    bool dir = ((i & k) == 0);
                    if ((a < bb) == dir) {
                        keys[i] = bb; keys[l] = a;
                        u32 p = pay[i]; pay[i] = pay[l]; pay[l] = p;
                    }
                }
            }
            __syncthreads();
        }
    }
    if (tid < 100) {
        u64 kk = keys[tid];      // n2 >= 256 > 100 always
        if (kk != 0) {
            u32 ci = 0xFFFFFFFFu - (u32)(kk & 0xFFFFFFFFull);
            float4 bx = svb[pay[tid]];
            out[b*400 + tid*4 + 0] = bx.x;
            out[b*400 + tid*4 + 1] = bx.y;
            out[b*400 + tid*4 + 2] = bx.z;
            out[b*400 + tid*4 + 3] = bx.w;
            out[800  + b*100 + tid] = __uint_as_float((u32)(kk >> 32));
            out[1000 + b*100 + tid] = (float)((ci % 80) + 1);
        } else {
            out[b*400 + tid*4 + 0] = 0.f; out[b*400 + tid*4 + 1] = 0.f;
            out[b*400 + tid*4 + 2] = 0.f; out[b*400 + tid*4 + 3] = 0.f;
            out[800  + b*100 + tid] = 0.f;
            out[1000 + b*100 + tid] = 0.f;
        }
    }
}

extern "C" void kernel_launch(void* const* d_in, const int* in_sizes, int n_in,
                              void* d_out, int out_size, void* d_ws, size_t ws_size,
                              hipStream_t stream)
{
    const float* features  = (const float*)d_in[0];
    const float* proposals = (const float*)d_in[1];
    const float* fc1_w = (const float*)d_in[2];
    const float* fc1_b = (const float*)d_in[3];
    const float* fc2_w = (const float*)d_in[4];
    const float* fc2_b = (const float*)d_in[5];
    const float* cls_w = (const float*)d_in[6];
    const float* cls_b = (const float*)d_in[7];
    const float* bbox_w = (const float*)d_in[8];
    const float* bbox_b = (const float*)d_in[9];
    const int* img_sz = (const int*)d_in[10];
    float* out = (float*)d_out;
    char* ws = (char*)d_ws;
    _Float16* xhi   = (_Float16*)(ws + XHI_OFF);
    _Float16* xlo   = (_Float16*)(ws + XLO_OFF);
    _Float16* wt1hi = (_Float16*)(ws + WT1HI_OFF);
    _Float16* wt1lo = (_Float16*)(ws + WT1LO_OFF);
    _Float16* wt2hi = (_Float16*)(ws + WT2HI_OFF);
    _Float16* wt2lo = (_Float16*)(ws + WT2LO_OFF);
    _Float16* h1hi  = (_Float16*)(ws + H1HI_OFF);
    _Float16* h1lo  = (_Float16*)(ws + H1LO_OFF);
    float*  h2     = (float*) (ws + H2_OFF);
    float*  cwT    = (float*) (ws + CWT_OFF);
    float*  bwT    = (float*) (ws + BWT_OFF);
    float*  probs  = (float*) (ws + PROBS_OFF);
    float*  cur    = (float*) (ws + CUR_OFF);
    int*    ccnt   = (int*)   (ws + CNT_OFF);
    float*  ccs    = (float*) (ws + CCS_OFF);
    float4* ccob   = (float4*)(ws + CCOB_OFF);
    float*  ccar   = (float*) (ws + CCAR_OFF);
    float4* ccbx   = (float4*)(ws + CCBX_OFF);
    int*    ccix   = (int*)   (ws + CCIX_OFF);
    float*  svs    = (float*) (ws + SVS_OFF);
    float4* svb    = (float4*)(ws + SVB_OFF);
    int*    svi    = (int*)   (ws + SVI_OFF);
    int*    svc    = (int*)   (ws + SVC_OFF);
    float*  part   = (float*) (ws + PART_OFF);

    init_kernel<<<1, 256, 0, stream>>>(ccnt);
    hipMemcpyAsync(cur, proposals, (size_t)NROWS*4*sizeof(float),
                   hipMemcpyDeviceToDevice, stream);
    trans_naive<<<(3*NCLS*HID + 255)/256, 256, 0, stream>>>(cls_w, cwT, HID, NCLS, 3);
    trans_naive<<<(3*4*HID + 255)/256, 256, 0, stream>>>(bbox_w, bwT, HID, 4, 3);

    for (int st = 0; st < 3; ++st) {
        roi_align_kernel<<<NROWS, 256, 0, stream>>>(features, cur, xhi, xlo);
        trans_limb<<<dim3(HID/32, INDIM/32), 256, 0, stream>>>(
            fc1_w + (size_t)st*INDIM*HID, wt1hi, wt1lo, INDIM, HID, 64.0f);
        // fc1: 392 K-steps; z=16 (8 z's x 25 steps + 8 x 24); 256 blocks = 1/CU
        mfma_gemm_limb256<<<256, 512, 131072, stream>>>(
            xhi, xlo, wt1hi, wt1lo, part, 24, 8);
        reduce_bias_relu<<<(NROWS*HID)/256, 256, 0, stream>>>(
            part, fc1_b + st*HID, nullptr, h1hi, h1lo, 16, 1);
        trans_limb<<<dim3(HID/32, HID/32), 256, 0, stream>>>(
            fc2_w + (size_t)st*HID*HID, wt2hi, wt2lo, HID, HID, 64.0f);
        // fc2: K=1024 = 32 K-steps; z=8 x 4 steps
        mfma_gemm_limb<<<512, 256, 0, stream>>>(
            h1hi, h1lo, wt2hi, wt2lo, part, 4, 0, 3);
        reduce_bias_relu<<<(NROWS*HID)/256, 256, 0, stream>>>(
            part, fc2_b + st*HID, h2, nullptr, nullptr, 8, 0);
        heads_kernel<<<NROWS/4, 512, 0, stream>>>(
            h2, cwT + (size_t)st*NCLS*HID, cls_b + st*NCLS,
            bwT + (size_t)st*4*HID, bbox_b + st*4,
            cur, probs, img_sz, st, st == 2 ? 1 : 0);
    }
    compact_class<<<(NB*CAND_PER_IMG)/256, 256, 0, stream>>>(
        probs, cur, img_sz, ccnt, ccs, ccob, ccar, ccbx, ccix);
    class_nms<<<160, 64, 0, stream>>>(
        ccnt, ccs, ccob, ccar, ccbx, ccix, svs, svb, svi, svc);
    merge_topk<<<NB, 256, 98304, stream>>>(
        svs, svb, svi, svc, out);
}

// Round 11
// 739.244 us; speedup vs baseline: 1.0568x; 1.0568x over previous
//
#include <hip/hip_runtime.h>
#include <math.h>

#define NPROP 512
#define NB 2
#define NROWS (NB*NPROP)          // 1024
#define FCH 256
#define FH 64
#define FW 64
#define INDIM (FCH*7*7)           // 12544
#define HID 1024
#define NCLS 81
#define CAND_PER_IMG (NPROP*(NCLS-1))  // 40960
#define CLIPV 4.1351666f          // log(1000/16) rounded to f32
#define RCHUNK 1792               // 12544 = 7 * 1792; 224 octets/chunk

typedef _Float16 f16x8 __attribute__((ext_vector_type(8)));
typedef float f32x4 __attribute__((ext_vector_type(4)));
typedef unsigned int u32;
typedef unsigned long long u64;

__device__ __forceinline__ void gload16(const void* g, void* l) {
    __builtin_amdgcn_global_load_lds((const __attribute__((address_space(1))) u32*)g,
                                     (__attribute__((address_space(3))) u32*)l, 16, 0, 0);
}

// Limb planes are k-octet-major: [K/8][1024][8] f16. Octet stride = 8192 elems.
// -> staging gload16 reads 64 consecutive 16B chunks (coalesced 1KB/instr).

// ---- workspace layout (bytes) ----
#define XHI_OFF    0ull
#define XLO_OFF    25690112ull
#define WT1HI_OFF  51380224ull
#define WT1LO_OFF  77070336ull
#define WT2HI_OFF  102760448ull
#define WT2LO_OFF  104857600ull
#define H1HI_OFF   106954752ull
#define H1LO_OFF   109051904ull
#define H2_OFF     111149056ull
#define CWT_OFF    115343360ull
#define BWT_OFF    116338688ull
#define PROBS_OFF  116387840ull
#define CUR_OFF    116719616ull
#define CNT_OFF    116736000ull   // ccnt[160] ints
#define CCS_OFF    116737024ull   // per-class scores   [160][512] f32
#define CCOB_OFF   117064704ull   // per-class off-box  [160][512] float4
#define CCAR_OFF   118375424ull   // per-class area     [160][512] f32
#define CCBX_OFF   118703104ull   // per-class box      [160][512] float4
#define CCIX_OFF   120013824ull   // per-class coidx    [160][512] int
#define SVS_OFF    120341504ull   // survivors score    [160][128] f32
#define SVB_OFF    120423424ull   // survivors box      [160][128] float4
#define SVI_OFF    120751104ull   // survivors coidx    [160][128] int
#define SVC_OFF    120833024ull   // survivor count     [160] int
#define PART_OFF   121489408ull   // 16 planes of 1024x1024 f32 = 67 MB

__global__ void init_kernel(int* ccnt) {
    if (threadIdx.x < 160) ccnt[threadIdx.x] = 0;
}

// 4 proposals per block (one wave each); LDS-staged transpose so the
// k-octet-major output is written as aligned 64B segments.
__global__ __launch_bounds__(256) void roi_align_kernel(
    const float* __restrict__ feat, const float* __restrict__ boxes,
    _Float16* __restrict__ Xhi, _Float16* __restrict__ Xlo)
{
    __shared__ __align__(16) _Float16 bufh[4][1800], bufl[4][1800];
    __shared__ int   sidx[4][4][49];
    __shared__ float swt[4][4][49];
    const int tid = threadIdx.x;
    const int w = tid >> 6, lane = tid & 63;
    const int r0 = blockIdx.x << 2;
    const int r = r0 + w;
    const int b = r >> 9;
    const float* f = feat + (size_t)b * (FCH*FH*FW);

    if (lane < 49) {
        float x1 = boxes[r*4+0]*0.125f, y1 = boxes[r*4+1]*0.125f;
        float x2 = boxes[r*4+2]*0.125f, y2 = boxes[r*4+3]*0.125f;
        float bw = fmaxf(x2-x1, 1.0f) / 7.0f;
        float bh = fmaxf(y2-y1, 1.0f) / 7.0f;
        int py = lane / 7, px = lane - py*7;
        float gx = x1 + ((float)px + 0.5f)*bw;
        float gy = y1 + ((float)py + 0.5f)*bh;
        gx = fminf(fmaxf(gx, 0.0f), 63.0f);
        gy = fminf(fmaxf(gy, 0.0f), 63.0f);
        float x0f = floorf(gx), y0f = floorf(gy);
        int x0 = (int)x0f, y0 = (int)y0f;
        int x1c = min(x0+1, 63), y1c = min(y0+1, 63);
        float dx = gx - x0f, dy = gy - y0f;
        sidx[w][0][lane] = y0*FW + x0;
        sidx[w][1][lane] = y0*FW + x1c;
        sidx[w][2][lane] = y1c*FW + x0;
        sidx[w][3][lane] = y1c*FW + x1c;
        swt[w][0][lane] = (1.0f-dy)*(1.0f-dx);
        swt[w][1][lane] = (1.0f-dy)*dx;
        swt[w][2][lane] = dy*(1.0f-dx);
        swt[w][3][lane] = dy*dx;
    }
    __syncthreads();
    for (int ch = 0; ch < 7; ++ch) {
        for (int i2 = lane; i2 < RCHUNK; i2 += 64) {
            int i = ch*RCHUNK + i2;
            int c = i / 49;
            int p = i - c*49;
            const float* fc = f + c*(FH*FW);
            float v = fc[sidx[w][0][p]]*swt[w][0][p] + fc[sidx[w][1][p]]*swt[w][1][p]
                    + fc[sidx[w][2][p]]*swt[w][2][p] + fc[sidx[w][3][p]]*swt[w][3][p];
            float vs = v * 32.0f;
            _Float16 h = (_Float16)vs;
            bufh[w][i2] = h;
            bufl[w][i2] = (_Float16)(vs - (float)h);
        }
        __syncthreads();
        // write-out: q = (oct<<2)|p; consecutive lanes -> 64B contiguous runs
        for (int q = tid; q < 224*4; q += 256) {
            int oct = q >> 2, p = q & 3;
            f16x8 hv = *(const f16x8*)&bufh[p][oct*8];
            f16x8 lv = *(const f16x8*)&bufl[p][oct*8];
            size_t idx = ((size_t)(ch*224 + oct) << 13) + ((size_t)(r0 + p) << 3);
            *(f16x8*)(Xhi + idx) = hv;
            *(f16x8*)(Xlo + idx) = lv;
        }
        __syncthreads();
    }
}

// in [K][N] fp32 -> hi/lo k-octet-major [(K/8)][N][8] f16 (scaled). N=1024.
// Write phase: lanes cover consecutive n of one octet -> 512B contiguous.
__global__ __launch_bounds__(256) void trans_limb(
    const float* __restrict__ in, _Float16* __restrict__ hi, _Float16* __restrict__ lo,
    int K, int N, float scale)
{
    __shared__ float t[32][33];
    int tx = threadIdx.x & 31, ty = threadIdx.x >> 5;   // ty 0..7
    int n0 = blockIdx.x << 5, k0 = blockIdx.y << 5;
#pragma unroll
    for (int r = 0; r < 4; ++r)
        t[ty + 8*r][tx] = in[(size_t)(k0 + ty + 8*r)*N + n0 + tx];
    __syncthreads();
    if (ty < 4) {                      // 4 octets per tile
        int n = n0 + tx;
        f16x8 hv, lv;
#pragma unroll
        for (int e = 0; e < 8; ++e) {
            float v = t[ty*8 + e][tx] * scale;
            _Float16 h = (_Float16)v;
            hv[e] = h;
            lv[e] = (_Float16)(v - (float)h);
        }
        size_t idx = (((size_t)(k0 >> 3) + ty)*N << 3) + ((size_t)n << 3);
        *(f16x8*)(hi + idx) = hv;
        *(f16x8*)(lo + idx) = lv;
    }
}

// batched plain transpose: in [b][K][N] -> out [b][N][K] (fp32, small)
__global__ __launch_bounds__(256) void trans_naive(
    const float* __restrict__ in, float* __restrict__ out, int K, int N, int batch)
{
    int idx = blockIdx.x*256 + threadIdx.x;
    int per = K*N;
    if (idx >= per*batch) return;
    int b = idx / per;
    int rem = idx - b*per;
    int n = rem / K, k = rem - n*K;
    out[idx] = in[(size_t)b*per + (size_t)k*N + n];
}

// ---------------------------------------------------------------------------
// fc1 GEMM: 256x256 tile, 8 waves (2x4), f16-limb MFMA, 128KB dynamic-LDS
// double buffer, counted vmcnt(8), coalesced k-octet-major staging.
// RACE FIX (r11): drain lgkmcnt + sched_barrier(0) BEFORE the second raw
// barrier -- rule #18: hipcc can sink register-only MFMAs (and their
// compiler-inserted lgkm waits) past inline-asm barriers, leaving ds_reads
// outstanding while other waves' global_load_lds overwrite the buffer.
// Grid = 16 z * 16 tiles = 256 blocks = 1/CU; z XCD-affine.
// ---------------------------------------------------------------------------
__global__ __launch_bounds__(512, 2) void mfma_gemm_limb256(
    const _Float16* __restrict__ Ahi, const _Float16* __restrict__ Alo,
    const _Float16* __restrict__ Bhi, const _Float16* __restrict__ Blo,
    float* __restrict__ part, int base, int extra)
{
    extern __shared__ __align__(16) char ldsraw[];   // 131072 bytes
    const int tid = threadIdx.x;
    const int lane = tid & 63;
    const int w = tid >> 6;            // 0..7
    const int wm = w >> 2, wn = w & 3; // wave tile: rows wm*128, cols wn*64
    const int kg = lane >> 4, lr = lane & 15;
    const int bid = blockIdx.x;
    const int z = bid & 15;
    const int tile = bid >> 4;
    const int bx = tile & 3, by = tile >> 2;
    const int row0 = by << 8, col0 = bx << 8;
    const int zsteps = base + (z < extra ? 1 : 0);
    const int o0 = ((z*base + (z < extra ? z : extra)) * 32) >> 3;  // start octet

    // staging: wave w owns plane w>>1 (0=Ah 1=Al 2=Bh 3=Bl), half (w&1)
    const int sp = w >> 1;
    const int sbase = (w & 1) * 8;
    const _Float16* pl = (sp == 0) ? Ahi : (sp == 1) ? Alo : (sp == 2) ? Bhi : Blo;
    const int rc0 = (sp < 2) ? row0 : col0;
    const _Float16* sG = pl + ((size_t)(rc0 + lane) << 3);   // per-lane, coalesced

    f32x4 acc[8][4];
#pragma unroll
    for (int i = 0; i < 8; ++i)
#pragma unroll
        for (int j = 0; j < 4; ++j) acc[i][j] = (f32x4){0.f, 0.f, 0.f, 0.f};

    auto STAGE = [&](int bufoff, int koct) {
#pragma unroll
        for (int j = 0; j < 8; ++j) {
            int sub = sbase + j;           // 0..15: ks = sub>>2, rblk = sub&3
            int ks = sub >> 2, rblk = sub & 3;
            const void* g = (const void*)(sG + ((size_t)(o0 + koct + ks) << 13)
                                             + ((size_t)rblk << 9));
            void* l = (void*)(ldsraw + bufoff + sp*16384 + ks*4096 + rblk*1024);
            gload16(g, l);                 // dest uniform; HW adds lane*16
        }
    };

    STAGE(0, 0);
    if (zsteps > 1) STAGE(65536, 4);

    for (int t = 0; t < zsteps; ++t) {
        if (t + 1 < zsteps) asm volatile("s_waitcnt vmcnt(8)" ::: "memory");
        else                asm volatile("s_waitcnt vmcnt(0)" ::: "memory");
        __builtin_amdgcn_s_barrier();          // all waves' stage of tile t done
        asm volatile("" ::: "memory");         // pin reads below barrier
        const char* Lb = ldsraw + ((t & 1) ? 65536 : 0);
        f16x8 Bh[4], Bl[4];
#pragma unroll
        for (int ni = 0; ni < 4; ++ni) {
            int s = (kg*256 + wn*64 + ni*16 + lr) * 16;
            Bh[ni] = *(const f16x8*)(Lb + 2*16384 + s);
            Bl[ni] = *(const f16x8*)(Lb + 3*16384 + s);
        }
#pragma unroll
        for (int mi = 0; mi < 8; ++mi) {       // A reads fused under MFMA
            int s = (kg*256 + wm*128 + mi*16 + lr) * 16;
            f16x8 ah = *(const f16x8*)(Lb + s);
            f16x8 al = *(const f16x8*)(Lb + 16384 + s);
#pragma unroll
            for (int ni = 0; ni < 4; ++ni) {
                acc[mi][ni] = __builtin_amdgcn_mfma_f32_16x16x32_f16(ah, Bh[ni], acc[mi][ni], 0, 0, 0);
                acc[mi][ni] = __builtin_amdgcn_mfma_f32_16x16x32_f16(ah, Bl[ni], acc[mi][ni], 0, 0, 0);
                acc[mi][ni] = __builtin_amdgcn_mfma_f32_16x16x32_f16(al, Bh[ni], acc[mi][ni], 0, 0, 0);
            }
        }
        // RACE FIX: all LDS reads drained + no instruction motion across this
        // point before we let other waves overwrite the buffer (rule #18).
        asm volatile("s_waitcnt lgkmcnt(0)" ::: "memory");
        __builtin_amdgcn_sched_barrier(0);
        __builtin_amdgcn_s_barrier();          // all waves done reading buf
        asm volatile("" ::: "memory");         // pin STAGE below barrier
        if (t + 2 < zsteps) STAGE((t & 1) ? 65536 : 0, (t+2)*4);
    }

    // epilogue: C/D layout col=lane&15, row=(lane>>4)*4+j
    float* cb = part + ((size_t)z << 20)
              + (size_t)row0*HID + col0 + wn*64 + lr;
#pragma unroll
    for (int mi = 0; mi < 8; ++mi) {
#pragma unroll
        for (int j = 0; j < 4; ++j) {
            int row = wm*128 + mi*16 + kg*4 + j;
            float* pr = cb + (size_t)row*HID;
            pr[0]  = acc[mi][0][j];
            pr[16] = acc[mi][1][j];
            pr[32] = acc[mi][2][j];
            pr[48] = acc[mi][3][j];
        }
    }
}

// ---------------------------------------------------------------------------
// fc2 GEMM: 128x128 tile, depth-2 dbuf, counted vmcnt; coalesced staging.
// ---------------------------------------------------------------------------
__global__ __launch_bounds__(256) void mfma_gemm_limb(
    const _Float16* __restrict__ Ahi, const _Float16* __restrict__ Alo,
    const _Float16* __restrict__ Bhi, const _Float16* __restrict__ Blo,
    float* __restrict__ part, int base, int extra, int lognz)
{
    __shared__ __align__(16) _Float16 lds[2][4][512][8];   // 2 x 32KB
    const int tid = threadIdx.x;
    const int lane = tid & 63;
    const int w = tid >> 6, wm = w >> 1, wn = w & 1;
    const int kg = lane >> 4, lr = lane & 15;
    const int bid = blockIdx.x;
    const int nzm = (1 << lognz) - 1;
    const int z = bid & nzm;
    const int bx = (bid >> lognz) & 7;
    const int by = bid >> (lognz + 3);
    const int row0 = by << 7, col0 = bx << 7;
    const int zsteps = base + (z < extra ? 1 : 0);
    const int o0 = ((z*base + (z < extra ? z : extra)) * 32) >> 3;
    const int r_ = tid & 127;
    const int ks1 = tid >> 7;          // 0 or 1
    const int wb = tid & 192;          // wave-uniform slot base

    const _Float16* srcA0 = Ahi + ((size_t)(row0 + r_) << 3);
    const _Float16* srcA1 = Alo + ((size_t)(row0 + r_) << 3);
    const _Float16* srcB0 = Bhi + ((size_t)(col0 + r_) << 3);
    const _Float16* srcB1 = Blo + ((size_t)(col0 + r_) << 3);

    f32x4 acc[4][4];
#pragma unroll
    for (int i = 0; i < 4; ++i)
#pragma unroll
        for (int j = 0; j < 4; ++j) acc[i][j] = (f32x4){0.f, 0.f, 0.f, 0.f};

#define STAGE(bf, oct) do { \
    _Float16* Lb = &lds[bf][0][0][0]; \
    gload16(srcA0 + ((size_t)(o0+(oct)+ks1  ) << 13), (void*)(Lb + (0*512 +       wb)*8)); \
    gload16(srcA0 + ((size_t)(o0+(oct)+ks1+2) << 13), (void*)(Lb + (0*512 + 256 + wb)*8)); \
    gload16(srcA1 + ((size_t)(o0+(oct)+ks1  ) << 13), (void*)(Lb + (1*512 +       wb)*8)); \
    gload16(srcA1 + ((size_t)(o0+(oct)+ks1+2) << 13), (void*)(Lb + (1*512 + 256 + wb)*8)); \
    gload16(srcB0 + ((size_t)(o0+(oct)+ks1  ) << 13), (void*)(Lb + (2*512 +       wb)*8)); \
    gload16(srcB0 + ((size_t)(o0+(oct)+ks1+2) << 13), (void*)(Lb + (2*512 + 256 + wb)*8)); \
    gload16(srcB1 + ((size_t)(o0+(oct)+ks1  ) << 13), (void*)(Lb + (3*512 +       wb)*8)); \
    gload16(srcB1 + ((size_t)(o0+(oct)+ks1+2) << 13), (void*)(Lb + (3*512 + 256 + wb)*8)); \
} while (0)

    STAGE(0, 0);
    if (1 < zsteps) STAGE(1, 4);
    for (int t = 0; t < zsteps; ++t) {
        if (t + 1 < zsteps) asm volatile("s_waitcnt vmcnt(8)" ::: "memory");
        else                asm volatile("s_waitcnt vmcnt(0)" ::: "memory");
        __builtin_amdgcn_s_barrier();
        const _Float16* Lr = &lds[t & 1][0][0][0];
        f16x8 Ah[4], Al[4], Bh[4], Bl[4];
#pragma unroll
        for (int mi = 0; mi < 4; ++mi) {
            int s = kg*128 + wm*64 + mi*16 + lr;
            Ah[mi] = *(const f16x8*)(Lr + (0*512 + s)*8);
            Al[mi] = *(const f16x8*)(Lr + (1*512 + s)*8);
        }
#pragma unroll
        for (int ni = 0; ni < 4; ++ni) {
            int s = kg*128 + wn*64 + ni*16 + lr;
            Bh[ni] = *(const f16x8*)(Lr + (2*512 + s)*8);
            Bl[ni] = *(const f16x8*)(Lr + (3*512 + s)*8);
        }
        asm volatile("s_waitcnt lgkmcnt(0)" ::: "memory");   // frag data in regs
        __builtin_amdgcn_sched_barrier(0);
        __builtin_amdgcn_s_barrier();                        // all waves done reading
        if (t + 2 < zsteps) STAGE(t & 1, (t+2)*4);           // overwrite just-read buf
#pragma unroll
        for (int mi = 0; mi < 4; ++mi)
#pragma unroll
            for (int ni = 0; ni < 4; ++ni) {
                acc[mi][ni] = __builtin_amdgcn_mfma_f32_16x16x32_f16(Ah[mi], Bh[ni], acc[mi][ni], 0, 0, 0);
                acc[mi][ni] = __builtin_amdgcn_mfma_f32_16x16x32_f16(Ah[mi], Bl[ni], acc[mi][ni], 0, 0, 0);
                acc[mi][ni] = __builtin_amdgcn_mfma_f32_16x16x32_f16(Al[mi], Bh[ni], acc[mi][ni], 0, 0, 0);
            }
    }
#undef STAGE

    // epilogue: C/D layout col=lane&15, row=(lane>>4)*4+j
    float* cb = part + ((size_t)z << 20)
              + (size_t)row0*HID + col0 + wn*64 + lr;
#pragma unroll
    for (int mi = 0; mi < 4; ++mi) {
#pragma unroll
        for (int j = 0; j < 4; ++j) {
            int row = wm*64 + mi*16 + kg*4 + j;
            float* pr = cb + (size_t)row*HID;
            pr[0]  = acc[mi][0][j];
            pr[16] = acc[mi][1][j];
            pr[32] = acc[mi][2][j];
            pr[48] = acc[mi][3][j];
        }
    }
}

// out = relu(sum_p part[p]/2048 + bias); mode 0: fp32 out; mode 1: f16 limb out
// (x32, k-octet-major)
__global__ __launch_bounds__(256) void reduce_bias_relu(
    const float* __restrict__ part, const float* __restrict__ bias,
    float* __restrict__ out32, _Float16* __restrict__ outhi, _Float16* __restrict__ outlo,
    int nsplit, int mode)
{
    int gid = blockIdx.x*256 + threadIdx.x;
    float s = 0.f;
    for (int p = 0; p < nsplit; ++p) s += part[((size_t)p << 20) + gid];
    s = s * (1.0f/2048.0f) + bias[gid & (HID-1)];
    s = fmaxf(s, 0.f);
    if (mode == 0) {
        out32[gid] = s;
    } else {
        float vs = s * 32.0f;
        _Float16 h = (_Float16)vs;
        int row = gid >> 10, col = gid & 1023;
        size_t idx = ((size_t)(col >> 3) << 13) + ((size_t)row << 3) + (col & 7);
        outhi[idx] = h;
        outlo[idx] = (_Float16)(vs - (float)h);
    }
}

// cls+bbox heads + decode (+softmax at last stage). 4 rows per block.
__global__ __launch_bounds__(512) void heads_kernel(
    const float* __restrict__ X, const float* __restrict__ cwT, const float* __restrict__ cb,
    const float* __restrict__ bwT, const float* __restrict__ bbb,
    float* __restrict__ cur, float* __restrict__ probs,
    const int* __restrict__ img_sz, int stage, int write_probs)
{
    __shared__ float xs[4][1024];
    __shared__ float lg[4][96];
    int tid = threadIdx.x;
    int lr = tid >> 7;           // local row 0..3
    int j  = tid & 127;
    int row0 = blockIdx.x * 4;
    for (int i = tid; i < 4096; i += 512)
        xs[i >> 10][i & 1023] = X[(size_t)(row0 + (i >> 10))*1024 + (i & 1023)];
    __syncthreads();
    int row = row0 + lr;
    if (j < 85) {
        const float* wrow = (j < 81) ? (cwT + (size_t)j*HID) : (bwT + (size_t)(j-81)*HID);
        float acc = (j < 81) ? cb[j] : bbb[j-81];
        const float4* w4 = (const float4*)wrow;
#pragma unroll 4
        for (int k4 = 0; k4 < 256; ++k4) {
            float4 wv = w4[k4];
            const float* xr = &xs[lr][k4*4];
            acc = fmaf(xr[0], wv.x, acc);
            acc = fmaf(xr[1], wv.y, acc);
            acc = fmaf(xr[2], wv.z, acc);
            acc = fmaf(xr[3], wv.w, acc);
        }
        lg[lr][j] = acc;
    }
    __syncthreads();
    if (j == 0) {   // box decode + clip
        float img = (float)(*img_sz);
        float px1 = cur[row*4+0], py1 = cur[row*4+1];
        float px2 = cur[row*4+2], py2 = cur[row*4+3];
        float pw = fmaxf(px2-px1, 1e-6f), ph = fmaxf(py2-py1, 1e-6f);
        float pcx = px1 + 0.5f*pw, pcy = py1 + 0.5f*ph;
        float wx, wy, ww, wh;
        if (stage == 0)      { wx=0.1f;   wy=0.1f;   ww=0.2f;   wh=0.2f;   }
        else if (stage == 1) { wx=0.05f;  wy=0.05f;  ww=0.1f;   wh=0.1f;   }
        else                 { wx=0.033f; wy=0.033f; ww=0.067f; wh=0.067f; }
        float dx = lg[lr][81]*wx, dy = lg[lr][82]*wy;
        float dw = fminf(lg[lr][83]*ww, CLIPV);
        float dh = fminf(lg[lr][84]*wh, CLIPV);
        float cx = dx*pw + pcx, cy = dy*ph + pcy;
        float w = expf(dw)*pw, h = expf(dh)*ph;
        cur[row*4+0] = fminf(fmaxf(cx - 0.5f*w, 0.f), img);
        cur[row*4+1] = fminf(fmaxf(cy - 0.5f*h, 0.f), img);
        cur[row*4+2] = fminf(fmaxf(cx + 0.5f*w, 0.f), img);
        cur[row*4+3] = fminf(fmaxf(cy + 0.5f*h, 0.f), img);
    }
    if (write_probs) {
        if (j == 1) {
            float m = lg[lr][0];
            for (int c2 = 1; c2 < 81; ++c2) m = fmaxf(m, lg[lr][c2]);
            float s = 0.f;
            for (int c2 = 0; c2 < 81; ++c2) s += expf(lg[lr][c2] - m);
            lg[lr][88] = m; lg[lr][89] = s;
        }
        __syncthreads();
        if (j < 81)
            probs[(size_t)row*81 + j] = expf(lg[lr][j] - lg[lr][88]) / lg[lr][89];
    }
}

// bucket passing candidates per (image,class); cross-class IoU is exactly 0
// (label offset trick), so NMS decomposes per class.
__global__ __launch_bounds__(256) void compact_class(
    const float* __restrict__ probs, const float* __restrict__ cur,
    const int* __restrict__ img_sz, int* __restrict__ ccnt,
    float* __restrict__ ccs, float4* __restrict__ ccob, float* __restrict__ ccar,
    float4* __restrict__ ccbx, int* __restrict__ ccix)
{
    int gid = blockIdx.x*256 + threadIdx.x;
    if (gid >= NB*CAND_PER_IMG) return;
    int b = gid / CAND_PER_IMG;
    int rem = gid - b*CAND_PER_IMG;
    int n = rem / 80;
    int cm = rem - n*80;
    int label = cm + 1;
    int r = b*NPROP + n;
    float s = probs[(size_t)r*81 + label];
    float b0 = cur[r*4+0], b1 = cur[r*4+1], b2 = cur[r*4+2], b3 = cur[r*4+3];
    if (s > 0.05f && (b2 - b0) >= 1.0f && (b3 - b1) >= 1.0f) {
        int cls = b*80 + cm;
        int pos = atomicAdd(&ccnt[cls], 1);
        int base = cls*512 + pos;
        float img = (float)(*img_sz);
        float t = (float)label * (img + 2.0f);
        float o0 = b0+t, o1 = b1+t, o2 = b2+t, o3 = b3+t;
        ccs[base] = s;
        ccob[base] = make_float4(o0, o1, o2, o3);
        ccar[base] = fmaxf(o2-o0, 0.f) * fmaxf(o3-o1, 0.f);
        ccbx[base] = make_float4(b0, b1, b2, b3);
        ccix[base] = rem;   // reference flat order for tie-break
    }
}

// one wave per (image,class): greedy NMS entirely in registers
__global__ __launch_bounds__(64) void class_nms(
    const int* __restrict__ ccnt, const float* __restrict__ ccs,
    const float4* __restrict__ ccob, const float* __restrict__ ccar,
    const float4* __restrict__ ccbx, const int* __restrict__ ccix,
    float* __restrict__ svs, float4* __restrict__ svb, int* __restrict__ svi,
    int* __restrict__ svc)
{
    int cls = blockIdx.x;          // 0..159
    int Nc = ccnt[cls];
    int base = cls*512;
    int lane = threadIdx.x;
    __shared__ float sel[5];
    float s[8]; float4 ob[8]; float a[8]; int ix[8];
    int cntl = 0;
    for (int j = lane; j < Nc; j += 64) {
        s[cntl] = ccs[base+j]; ob[cntl] = ccob[base+j];
        a[cntl] = ccar[base+j]; ix[cntl] = ccix[base+j];
        ++cntl;
    }
    int svn = 0;
    int rounds = (Nc < 100) ? Nc : 100;
    for (int it = 0; it < rounds; ++it) {
        float bs = -1.f; int bi = 0x7fffffff;
        for (int q = 0; q < cntl; ++q)
            if (s[q] > bs || (s[q] == bs && ix[q] < bi)) { bs = s[q]; bi = ix[q]; }
        for (int off = 32; off > 0; off >>= 1) {
            float os = __shfl_xor(bs, off);
            int oi = __shfl_xor(bi, off);
            if (os > bs || (os == bs && oi < bi)) { bs = os; bi = oi; }
        }
        if (bs <= 0.f) break;      // uniform across wave
        for (int q = 0; q < cntl; ++q) {
            if (s[q] == bs && ix[q] == bi) {   // unique owner (ix unique)
                sel[0] = ob[q].x; sel[1] = ob[q].y; sel[2] = ob[q].z; sel[3] = ob[q].w;
                sel[4] = a[q];
                int slot = cls*128 + svn;
                svs[slot] = bs;
                svb[slot] = ccbx[base + lane + q*64];
                svi[slot] = bi;
                s[q] = -1.f;
            }
        }
        __syncthreads();
        float bi0 = sel[0], bi1 = sel[1], bi2 = sel[2], bi3 = sel[3], ai = sel[4];
        for (int q = 0; q < cntl; ++q) {
            if (s[q] > 0.f) {
                float ix1 = fmaxf(bi0, ob[q].x), iy1 = fmaxf(bi1, ob[q].y);
                float ix2 = fminf(bi2, ob[q].z), iy2 = fminf(bi3, ob[q].w);
                float inter = fmaxf(ix2-ix1, 0.f) * fmaxf(iy2-iy1, 0.f);
                float iou = inter / (ai + a[q] - inter + 1e-9f);
                if (iou > 0.5f) s[q] = -1.f;
            }
        }
        ++svn;
        __syncthreads();
    }
    if (lane == 0) svc[cls] = svn;
}

// per image: bitonic-sort survivors by (score desc, coidx asc), write top-100.
// key = (score_bits << 32) | (~coidx); invalid slots key=0 sort last.
__global__ __launch_bounds__(256) void merge_topk(
    const float* __restrict__ svs, const float4* __restrict__ svb,
    const int* __restrict__ svi, const int* __restrict__ svc,
    float* __restrict__ out)
{
    extern __shared__ char smem[];
    u64* keys = (u64*)smem;                 // [8192] 64KB
    u32* pay  = (u32*)(smem + 65536);       // [8192] 32KB
    __shared__ int off[81];
    __shared__ int n2s;
    int b = blockIdx.x, tid = threadIdx.x;
    if (tid == 0) {
        int run = 0;
        for (int c = 0; c < 80; ++c) { off[c] = run; run += svc[b*80 + c]; }
        off[80] = run;
        int n2 = 256;
        while (n2 < run) n2 <<= 1;
        n2s = n2;
    }
    __syncthreads();
    int Ns = off[80], n2 = n2s;
    for (int c = 0; c < 80; ++c) {
        int n = off[c+1] - off[c];
        int srcb = (b*80 + c)*128;
        for (int k = tid; k < n; k += 256) {
            int src = srcb + k;
            keys[off[c] + k] = ((u64)__float_as_uint(svs[src]) << 32)
                             | (u64)(0xFFFFFFFFu - (u32)svi[src]);
            pay[off[c] + k] = src;
        }
    }
    for (int i = Ns + tid; i < n2; i += 256) { keys[i] = 0; pay[i] = 0; }
    __syncthreads();
    for (int k = 2; k <= n2; k <<= 1) {
        for (int j = k >> 1; j > 0; j >>= 1) {
            for (int i = tid; i < n2; i += 256) {
                int l = i ^ j;
                if (l > i) {
                    u64 a = keys[i], bb = keys[l];
                    bool dir = ((i & k) == 0);
                    if ((a < bb) == dir) {
                        keys[i] = bb; keys[l] = a;
                        u32 p = pay[i]; pay[i] = pay[l]; pay[l] = p;
                    }
                }
            }
            __syncthreads();
        }
    }
    if (tid < 100) {
        u64 kk = keys[tid];      // n2 >= 256 > 100 always
        if (kk != 0) {
            u32 ci = 0xFFFFFFFFu - (u32)(kk & 0xFFFFFFFFull);
            float4 bx = svb[pay[tid]];
            out[b*400 + tid*4 + 0] = bx.x;
            out[b*400 + tid*4 + 1] = bx.y;
            out[b*400 + tid*4 + 2] = bx.z;
            out[b*400 + tid*4 + 3] = bx.w;
            out[800  + b*100 + tid] = __uint_as_float((u32)(kk >> 32));
            out[1000 + b*100 + tid] = (float)((ci % 80) + 1);
        } else {
            out[b*400 + tid*4 + 0] = 0.f; out[b*400 + tid*4 + 1] = 0.f;
            out[b*400 + tid*4 + 2] = 0.f; out[b*400 + tid*4 + 3] = 0.f;
            out[800  + b*100 + tid] = 0.f;
            out[1000 + b*100 + tid] = 0.f;
        }
    }
}

extern "C" void kernel_launch(void* const* d_in, const int* in_sizes, int n_in,
                              void* d_out, int out_size, void* d_ws, size_t ws_size,
                              hipStream_t stream)
{
    const float* features  = (const float*)d_in[0];
    const float* proposals = (const float*)d_in[1];
    const float* fc1_w = (const float*)d_in[2];
    const float* fc1_b = (const float*)d_in[3];
    const float* fc2_w = (const float*)d_in[4];
    const float* fc2_b = (const float*)d_in[5];
    const float* cls_w = (const float*)d_in[6];
    const float* cls_b = (const float*)d_in[7];
    const float* bbox_w = (const float*)d_in[8];
    const float* bbox_b = (const float*)d_in[9];
    const int* img_sz = (const int*)d_in[10];
    float* out = (float*)d_out;
    char* ws = (char*)d_ws;
    _Float16* xhi   = (_Float16*)(ws + XHI_OFF);
    _Float16* xlo   = (_Float16*)(ws + XLO_OFF);
    _Float16* wt1hi = (_Float16*)(ws + WT1HI_OFF);
    _Float16* wt1lo = (_Float16*)(ws + WT1LO_OFF);
    _Float16* wt2hi = (_Float16*)(ws + WT2HI_OFF);
    _Float16* wt2lo = (_Float16*)(ws + WT2LO_OFF);
    _Float16* h1hi  = (_Float16*)(ws + H1HI_OFF);
    _Float16* h1lo  = (_Float16*)(ws + H1LO_OFF);
    float*  h2     = (float*) (ws + H2_OFF);
    float*  cwT    = (float*) (ws + CWT_OFF);
    float*  bwT    = (float*) (ws + BWT_OFF);
    float*  probs  = (float*) (ws + PROBS_OFF);
    float*  cur    = (float*) (ws + CUR_OFF);
    int*    ccnt   = (int*)   (ws + CNT_OFF);
    float*  ccs    = (float*) (ws + CCS_OFF);
    float4* ccob   = (float4*)(ws + CCOB_OFF);
    float*  ccar   = (float*) (ws + CCAR_OFF);
    float4* ccbx   = (float4*)(ws + CCBX_OFF);
    int*    ccix   = (int*)   (ws + CCIX_OFF);
    float*  svs    = (float*) (ws + SVS_OFF);
    float4* svb    = (float4*)(ws + SVB_OFF);
    int*    svi    = (int*)   (ws + SVI_OFF);
    int*    svc    = (int*)   (ws + SVC_OFF);
    float*  part   = (float*) (ws + PART_OFF);

    init_kernel<<<1, 256, 0, stream>>>(ccnt);
    hipMemcpyAsync(cur, proposals, (size_t)NROWS*4*sizeof(float),
                   hipMemcpyDeviceToDevice, stream);
    trans_naive<<<(3*NCLS*HID + 255)/256, 256, 0, stream>>>(cls_w, cwT, HID, NCLS, 3);
    trans_naive<<<(3*4*HID + 255)/256, 256, 0, stream>>>(bbox_w, bwT, HID, 4, 3);

    for (int st = 0; st < 3; ++st) {
        roi_align_kernel<<<NROWS/4, 256, 0, stream>>>(features, cur, xhi, xlo);
        trans_limb<<<dim3(HID/32, INDIM/32), 256, 0, stream>>>(
            fc1_w + (size_t)st*INDIM*HID, wt1hi, wt1lo, INDIM, HID, 64.0f);
        // fc1: 392 K-steps; z=16 (8 z's x 25 steps + 8 x 24); 256 blocks = 1/CU
        mfma_gemm_limb256<<<256, 512, 131072, stream>>>(
            xhi, xlo, wt1hi, wt1lo, part, 24, 8);
        reduce_bias_relu<<<(NROWS*HID)/256, 256, 0, stream>>>(
            part, fc1_b + st*HID, nullptr, h1hi, h1lo, 16, 1);
        trans_limb<<<dim3(HID/32, HID/32), 256, 0, stream>>>(
            fc2_w + (size_t)st*HID*HID, wt2hi, wt2lo, HID, HID, 64.0f);
        // fc2: K=1024 = 32 K-steps; z=8 x 4 steps
        mfma_gemm_limb<<<512, 256, 0, stream>>>(
            h1hi, h1lo, wt2hi, wt2lo, part, 4, 0, 3);
        reduce_bias_relu<<<(NROWS*HID)/256, 256, 0, stream>>>(
            part, fc2_b + st*HID, h2, nullptr, nullptr, 8, 0);
        heads_kernel<<<NROWS/4, 512, 0, stream>>>(
            h2, cwT + (size_t)st*NCLS*HID, cls_b + st*NCLS,
            bwT + (size_t)st*4*HID, bbox_b + st*4,
            cur, probs, img_sz, st, st == 2 ? 1 : 0);
    }
    compact_class<<<(NB*CAND_PER_IMG)/256, 256, 0, stream>>>(
        probs, cur, img_sz, ccnt, ccs, ccob, ccar, ccbx, ccix);
    class_nms<<<160, 64, 0, stream>>>(
        ccnt, ccs, ccob, ccar, ccbx, ccix, svs, svb, svi, svc);
    merge_topk<<<NB, 256, 98304, stream>>>(
        svs, svb, svi, svc, out);
}

// Round 12
// 694.446 us; speedup vs baseline: 1.1250x; 1.0645x over previous
//
#include <hip/hip_runtime.h>
#include <math.h>

#define NPROP 512
#define NB 2
#define NROWS (NB*NPROP)          // 1024
#define FCH 256
#define FH 64
#define FW 64
#define INDIM (FCH*7*7)           // 12544
#define HID 1024
#define NCLS 81
#define CAND_PER_IMG (NPROP*(NCLS-1))  // 40960
#define CLIPV 4.1351666f          // log(1000/16) rounded to f32
#define RCHUNK 1792               // 12544 = 7 * 1792; 224 octets/chunk

typedef _Float16 f16x8 __attribute__((ext_vector_type(8)));
typedef float f32x4 __attribute__((ext_vector_type(4)));
typedef unsigned int u32;
typedef unsigned long long u64;

__device__ __forceinline__ void gload16(const void* g, void* l) {
    __builtin_amdgcn_global_load_lds((const __attribute__((address_space(1))) u32*)g,
                                     (__attribute__((address_space(3))) u32*)l, 16, 0, 0);
}

// Limb planes are k-octet-major: [K/8][1024][8] f16. Octet stride = 8192 elems.

// ---- workspace layout (bytes) ----
#define XHI_OFF    0ull
#define XLO_OFF    25690112ull
#define WT1HI_OFF  51380224ull
#define WT1LO_OFF  77070336ull
#define WT2HI_OFF  102760448ull
#define WT2LO_OFF  104857600ull
#define H1HI_OFF   106954752ull
#define H1LO_OFF   109051904ull
#define H2_OFF     111149056ull
#define CWT_OFF    115343360ull
#define BWT_OFF    116338688ull
#define PROBS_OFF  116387840ull
#define CUR_OFF    116719616ull
#define CNT_OFF    116736000ull   // ccnt[160] ints
#define CCS_OFF    116737024ull   // per-class scores   [160][512] f32
#define CCOB_OFF   117064704ull   // per-class off-box  [160][512] float4
#define CCAR_OFF   118375424ull   // per-class area     [160][512] f32
#define CCBX_OFF   118703104ull   // per-class box      [160][512] float4
#define CCIX_OFF   120013824ull   // per-class coidx    [160][512] int
#define SVS_OFF    120341504ull   // survivors score    [160][128] f32
#define SVB_OFF    120423424ull   // survivors box      [160][128] float4
#define SVI_OFF    120751104ull   // survivors coidx    [160][128] int
#define SVC_OFF    120833024ull   // survivor count     [160] int
#define PART_OFF   121489408ull   // 16 planes of 1024x1024 f32 = 67 MB

// prep: head-weight transposes (cls+bbox, all stages) + ccnt init. grid 1020.
__global__ __launch_bounds__(256) void prep_kernel(
    const float* __restrict__ cls_w, const float* __restrict__ bbox_w,
    float* __restrict__ cwT, float* __restrict__ bwT, int* __restrict__ ccnt)
{
    int bid = blockIdx.x, tid = threadIdx.x;
    if (bid == 0 && tid < 160) ccnt[tid] = 0;
    int gid = bid*256 + tid;
    if (gid < 3*NCLS*HID) {            // cls: [3][1024][81] -> [3][81][1024]
        int per = NCLS*HID;
        int b = gid / per, rem = gid - b*per;
        int n = rem / HID, k = rem - n*HID;
        cwT[gid] = cls_w[(size_t)b*per + (size_t)k*NCLS + n];
    } else {
        int g2 = gid - 3*NCLS*HID;     // bbox: [3][1024][4] -> [3][4][1024]
        int per = 4*HID;
        int b = g2 / per, rem = g2 - b*per;
        int n = rem / HID, k = rem - n*HID;
        bwT[g2] = bbox_w[(size_t)b*per + (size_t)k*4 + n];
    }
}

// ---------------------------------------------------------------------------
// FUSED: roi_align (blocks 0..255) || trans_limb fc1_w (blocks 256..12799).
// Independent inputs -> overlap roi's gather latency with tl's streaming BW.
// ---------------------------------------------------------------------------
__global__ __launch_bounds__(256) void roi_tl1_kernel(
    const float* __restrict__ feat, const float* __restrict__ boxes,
    _Float16* __restrict__ Xhi, _Float16* __restrict__ Xlo,
    const float* __restrict__ w_in, _Float16* __restrict__ whi, _Float16* __restrict__ wlo)
{
    __shared__ __align__(16) _Float16 bufh[4][1800], bufl[4][1800];
    __shared__ int   sidx[4][4][49];
    __shared__ float swt[4][4][49];
    __shared__ float t[32][33];
    const int tid = threadIdx.x;
    const int bid = blockIdx.x;

    if (bid < 256) {
        // ---- roi_align: 4 proposals, one wave each; LDS-staged transpose ----
        const int w = tid >> 6, lane = tid & 63;
        const int r0 = bid << 2;
        const int r = r0 + w;
        const int b = r >> 9;
        const float* f = feat + (size_t)b * (FCH*FH*FW);
        if (lane < 49) {
            float x1 = boxes[r*4+0]*0.125f, y1 = boxes[r*4+1]*0.125f;
            float x2 = boxes[r*4+2]*0.125f, y2 = boxes[r*4+3]*0.125f;
            float bw = fmaxf(x2-x1, 1.0f) / 7.0f;
            float bh = fmaxf(y2-y1, 1.0f) / 7.0f;
            int py = lane / 7, px = lane - py*7;
            float gx = x1 + ((float)px + 0.5f)*bw;
            float gy = y1 + ((float)py + 0.5f)*bh;
            gx = fminf(fmaxf(gx, 0.0f), 63.0f);
            gy = fminf(fmaxf(gy, 0.0f), 63.0f);
            float x0f = floorf(gx), y0f = floorf(gy);
            int x0 = (int)x0f, y0 = (int)y0f;
            int x1c = min(x0+1, 63), y1c = min(y0+1, 63);
            float dx = gx - x0f, dy = gy - y0f;
            sidx[w][0][lane] = y0*FW + x0;
            sidx[w][1][lane] = y0*FW + x1c;
            sidx[w][2][lane] = y1c*FW + x0;
            sidx[w][3][lane] = y1c*FW + x1c;
            swt[w][0][lane] = (1.0f-dy)*(1.0f-dx);
            swt[w][1][lane] = (1.0f-dy)*dx;
            swt[w][2][lane] = dy*(1.0f-dx);
            swt[w][3][lane] = dy*dx;
        }
        __syncthreads();
        for (int ch = 0; ch < 7; ++ch) {
            for (int i2 = lane; i2 < RCHUNK; i2 += 64) {
                int i = ch*RCHUNK + i2;
                int c = i / 49;
                int p = i - c*49;
                const float* fc = f + c*(FH*FW);
                float v = fc[sidx[w][0][p]]*swt[w][0][p] + fc[sidx[w][1][p]]*swt[w][1][p]
                        + fc[sidx[w][2][p]]*swt[w][2][p] + fc[sidx[w][3][p]]*swt[w][3][p];
                float vs = v * 32.0f;
                _Float16 h = (_Float16)vs;
                bufh[w][i2] = h;
                bufl[w][i2] = (_Float16)(vs - (float)h);
            }
            __syncthreads();
            for (int q = tid; q < 224*4; q += 256) {
                int oct = q >> 2, p = q & 3;
                f16x8 hv = *(const f16x8*)&bufh[p][oct*8];
                f16x8 lv = *(const f16x8*)&bufl[p][oct*8];
                size_t idx = ((size_t)(ch*224 + oct) << 13) + ((size_t)(r0 + p) << 3);
                *(f16x8*)(Xhi + idx) = hv;
                *(f16x8*)(Xlo + idx) = lv;
            }
            __syncthreads();
        }
    } else {
        // ---- trans_limb fc1_w: [12544][1024] -> octet-major limbs ----
        const int bid2 = bid - 256;
        const int tx = tid & 31, ty = tid >> 5;
        const int n0 = (bid2 & 31) << 5, k0 = (bid2 >> 5) << 5;
#pragma unroll
        for (int r = 0; r < 4; ++r)
            t[ty + 8*r][tx] = w_in[(size_t)(k0 + ty + 8*r)*HID + n0 + tx];
        __syncthreads();
        if (ty < 4) {
            int n = n0 + tx;
            f16x8 hv, lv;
#pragma unroll
            for (int e = 0; e < 8; ++e) {
                float v = t[ty*8 + e][tx] * 64.0f;
                _Float16 h = (_Float16)v;
                hv[e] = h;
                lv[e] = (_Float16)(v - (float)h);
            }
            size_t idx = (((size_t)(k0 >> 3) + ty)*HID << 3) + ((size_t)n << 3);
            *(f16x8*)(whi + idx) = hv;
            *(f16x8*)(wlo + idx) = lv;
        }
    }
}

// ---------------------------------------------------------------------------
// FUSED: reduce1 (blocks 0..4095, h1 limbs) || trans_limb fc2_w (4096..5119).
// ---------------------------------------------------------------------------
__global__ __launch_bounds__(256) void red1_tl2_kernel(
    const float* __restrict__ part, const float* __restrict__ bias,
    _Float16* __restrict__ outhi, _Float16* __restrict__ outlo,
    const float* __restrict__ w_in, _Float16* __restrict__ whi, _Float16* __restrict__ wlo)
{
    __shared__ float t[32][33];
    const int tid = threadIdx.x;
    const int bid = blockIdx.x;
    if (bid < 4096) {
        int gid = bid*256 + tid;
        float s = 0.f;
        for (int p = 0; p < 16; ++p) s += part[((size_t)p << 20) + gid];
        s = s * (1.0f/2048.0f) + bias[gid & (HID-1)];
        s = fmaxf(s, 0.f);
        float vs = s * 32.0f;
        _Float16 h = (_Float16)vs;
        int row = gid >> 10, col = gid & 1023;
        size_t idx = ((size_t)(col >> 3) << 13) + ((size_t)row << 3) + (col & 7);
        outhi[idx] = h;
        outlo[idx] = (_Float16)(vs - (float)h);
    } else {
        const int bid2 = bid - 4096;
        const int tx = tid & 31, ty = tid >> 5;
        const int n0 = (bid2 & 31) << 5, k0 = (bid2 >> 5) << 5;
#pragma unroll
        for (int r = 0; r < 4; ++r)
            t[ty + 8*r][tx] = w_in[(size_t)(k0 + ty + 8*r)*HID + n0 + tx];
        __syncthreads();
        if (ty < 4) {
            int n = n0 + tx;
            f16x8 hv, lv;
#pragma unroll
            for (int e = 0; e < 8; ++e) {
                float v = t[ty*8 + e][tx] * 64.0f;
                _Float16 h = (_Float16)v;
                hv[e] = h;
                lv[e] = (_Float16)(v - (float)h);
            }
            size_t idx = (((size_t)(k0 >> 3) + ty)*HID << 3) + ((size_t)n << 3);
            *(f16x8*)(whi + idx) = hv;
            *(f16x8*)(wlo + idx) = lv;
        }
    }
}

// ---------------------------------------------------------------------------
// fc1 GEMM: 256x256 tile, 8 waves (2x4), f16-limb MFMA, 128KB dynamic-LDS
// double buffer, counted vmcnt(8), coalesced k-octet-major staging.
// lgkmcnt drain + sched_barrier(0) before second barrier (rule #18 race fix).
// ---------------------------------------------------------------------------
__global__ __launch_bounds__(512, 2) void mfma_gemm_limb256(
    const _Float16* __restrict__ Ahi, const _Float16* __restrict__ Alo,
    const _Float16* __restrict__ Bhi, const _Float16* __restrict__ Blo,
    float* __restrict__ part, int base, int extra)
{
    extern __shared__ __align__(16) char ldsraw[];   // 131072 bytes
    const int tid = threadIdx.x;
    const int lane = tid & 63;
    const int w = tid >> 6;            // 0..7
    const int wm = w >> 2, wn = w & 3; // wave tile: rows wm*128, cols wn*64
    const int kg = lane >> 4, lr = lane & 15;
    const int bid = blockIdx.x;
    const int z = bid & 15;
    const int tile = bid >> 4;
    const int bx = tile & 3, by = tile >> 2;
    const int row0 = by << 8, col0 = bx << 8;
    const int zsteps = base + (z < extra ? 1 : 0);
    const int o0 = ((z*base + (z < extra ? z : extra)) * 32) >> 3;  // start octet

    const int sp = w >> 1;
    const int sbase = (w & 1) * 8;
    const _Float16* pl = (sp == 0) ? Ahi : (sp == 1) ? Alo : (sp == 2) ? Bhi : Blo;
    const int rc0 = (sp < 2) ? row0 : col0;
    const _Float16* sG = pl + ((size_t)(rc0 + lane) << 3);   // per-lane, coalesced

    f32x4 acc[8][4];
#pragma unroll
    for (int i = 0; i < 8; ++i)
#pragma unroll
        for (int j = 0; j < 4; ++j) acc[i][j] = (f32x4){0.f, 0.f, 0.f, 0.f};

    auto STAGE = [&](int bufoff, int koct) {
#pragma unroll
        for (int j = 0; j < 8; ++j) {
            int sub = sbase + j;           // 0..15: ks = sub>>2, rblk = sub&3
            int ks = sub >> 2, rblk = sub & 3;
            const void* g = (const void*)(sG + ((size_t)(o0 + koct + ks) << 13)
                                             + ((size_t)rblk << 9));
            void* l = (void*)(ldsraw + bufoff + sp*16384 + ks*4096 + rblk*1024);
            gload16(g, l);                 // dest uniform; HW adds lane*16
        }
    };

    STAGE(0, 0);
    if (zsteps > 1) STAGE(65536, 4);

    for (int t = 0; t < zsteps; ++t) {
        if (t + 1 < zsteps) asm volatile("s_waitcnt vmcnt(8)" ::: "memory");
        else                asm volatile("s_waitcnt vmcnt(0)" ::: "memory");
        __builtin_amdgcn_s_barrier();          // all waves' stage of tile t done
        asm volatile("" ::: "memory");
        const char* Lb = ldsraw + ((t & 1) ? 65536 : 0);
        f16x8 Bh[4], Bl[4];
#pragma unroll
        for (int ni = 0; ni < 4; ++ni) {
            int s = (kg*256 + wn*64 + ni*16 + lr) * 16;
            Bh[ni] = *(const f16x8*)(Lb + 2*16384 + s);
            Bl[ni] = *(const f16x8*)(Lb + 3*16384 + s);
        }
#pragma unroll
        for (int mi = 0; mi < 8; ++mi) {       // A reads fused under MFMA
            int s = (kg*256 + wm*128 + mi*16 + lr) * 16;
            f16x8 ah = *(const f16x8*)(Lb + s);
            f16x8 al = *(const f16x8*)(Lb + 16384 + s);
#pragma unroll
            for (int ni = 0; ni < 4; ++ni) {
                acc[mi][ni] = __builtin_amdgcn_mfma_f32_16x16x32_f16(ah, Bh[ni], acc[mi][ni], 0, 0, 0);
                acc[mi][ni] = __builtin_amdgcn_mfma_f32_16x16x32_f16(ah, Bl[ni], acc[mi][ni], 0, 0, 0);
                acc[mi][ni] = __builtin_amdgcn_mfma_f32_16x16x32_f16(al, Bh[ni], acc[mi][ni], 0, 0, 0);
            }
        }
        // RACE FIX (rule #18): drain LDS reads, pin order, then barrier.
        asm volatile("s_waitcnt lgkmcnt(0)" ::: "memory");
        __builtin_amdgcn_sched_barrier(0);
        __builtin_amdgcn_s_barrier();          // all waves done reading buf
        asm volatile("" ::: "memory");
        if (t + 2 < zsteps) STAGE((t & 1) ? 65536 : 0, (t+2)*4);
    }

    // epilogue: C/D layout col=lane&15, row=(lane>>4)*4+j
    float* cb = part + ((size_t)z << 20)
              + (size_t)row0*HID + col0 + wn*64 + lr;
#pragma unroll
    for (int mi = 0; mi < 8; ++mi) {
#pragma unroll
        for (int j = 0; j < 4; ++j) {
            int row = wm*128 + mi*16 + kg*4 + j;
            float* pr = cb + (size_t)row*HID;
            pr[0]  = acc[mi][0][j];
            pr[16] = acc[mi][1][j];
            pr[32] = acc[mi][2][j];
            pr[48] = acc[mi][3][j];
        }
    }
}

// ---------------------------------------------------------------------------
// fc2 GEMM: 128x128 tile, depth-2 dbuf, counted vmcnt; coalesced staging.
// ---------------------------------------------------------------------------
__global__ __launch_bounds__(256) void mfma_gemm_limb(
    const _Float16* __restrict__ Ahi, const _Float16* __restrict__ Alo,
    const _Float16* __restrict__ Bhi, const _Float16* __restrict__ Blo,
    float* __restrict__ part, int base, int extra, int lognz)
{
    __shared__ __align__(16) _Float16 lds[2][4][512][8];   // 2 x 32KB
    const int tid = threadIdx.x;
    const int lane = tid & 63;
    const int w = tid >> 6, wm = w >> 1, wn = w & 1;
    const int kg = lane >> 4, lr = lane & 15;
    const int bid = blockIdx.x;
    const int nzm = (1 << lognz) - 1;
    const int z = bid & nzm;
    const int bx = (bid >> lognz) & 7;
    const int by = bid >> (lognz + 3);
    const int row0 = by << 7, col0 = bx << 7;
    const int zsteps = base + (z < extra ? 1 : 0);
    const int o0 = ((z*base + (z < extra ? z : extra)) * 32) >> 3;
    const int r_ = tid & 127;
    const int ks1 = tid >> 7;          // 0 or 1
    const int wb = tid & 192;          // wave-uniform slot base

    const _Float16* srcA0 = Ahi + ((size_t)(row0 + r_) << 3);
    const _Float16* srcA1 = Alo + ((size_t)(row0 + r_) << 3);
    const _Float16* srcB0 = Bhi + ((size_t)(col0 + r_) << 3);
    const _Float16* srcB1 = Blo + ((size_t)(col0 + r_) << 3);

    f32x4 acc[4][4];
#pragma unroll
    for (int i = 0; i < 4; ++i)
#pragma unroll
        for (int j = 0; j < 4; ++j) acc[i][j] = (f32x4){0.f, 0.f, 0.f, 0.f};

#define STAGE(bf, oct) do { \
    _Float16* Lb = &lds[bf][0][0][0]; \
    gload16(srcA0 + ((size_t)(o0+(oct)+ks1  ) << 13), (void*)(Lb + (0*512 +       wb)*8)); \
    gload16(srcA0 + ((size_t)(o0+(oct)+ks1+2) << 13), (void*)(Lb + (0*512 + 256 + wb)*8)); \
    gload16(srcA1 + ((size_t)(o0+(oct)+ks1  ) << 13), (void*)(Lb + (1*512 +       wb)*8)); \
    gload16(srcA1 + ((size_t)(o0+(oct)+ks1+2) << 13), (void*)(Lb + (1*512 + 256 + wb)*8)); \
    gload16(srcB0 + ((size_t)(o0+(oct)+ks1  ) << 13), (void*)(Lb + (2*512 +       wb)*8)); \
    gload16(srcB0 + ((size_t)(o0+(oct)+ks1+2) << 13), (void*)(Lb + (2*512 + 256 + wb)*8)); \
    gload16(srcB1 + ((size_t)(o0+(oct)+ks1  ) << 13), (void*)(Lb + (3*512 +       wb)*8)); \
    gload16(srcB1 + ((size_t)(o0+(oct)+ks1+2) << 13), (void*)(Lb + (3*512 + 256 + wb)*8)); \
} while (0)

    STAGE(0, 0);
    if (1 < zsteps) STAGE(1, 4);
    for (int t = 0; t < zsteps; ++t) {
        if (t + 1 < zsteps) asm volatile("s_waitcnt vmcnt(8)" ::: "memory");
        else                asm volatile("s_waitcnt vmcnt(0)" ::: "memory");
        __builtin_amdgcn_s_barrier();
        const _Float16* Lr = &lds[t & 1][0][0][0];
        f16x8 Ah[4], Al[4], Bh[4], Bl[4];
#pragma unroll
        for (int mi = 0; mi < 4; ++mi) {
            int s = kg*128 + wm*64 + mi*16 + lr;
            Ah[mi] = *(const f16x8*)(Lr + (0*512 + s)*8);
            Al[mi] = *(const f16x8*)(Lr + (1*512 + s)*8);
        }
#pragma unroll
        for (int ni = 0; ni < 4; ++ni) {
            int s = kg*128 + wn*64 + ni*16 + lr;
            Bh[ni] = *(const f16x8*)(Lr + (2*512 + s)*8);
            Bl[ni] = *(const f16x8*)(Lr + (3*512 + s)*8);
        }
        asm volatile("s_waitcnt lgkmcnt(0)" ::: "memory");   // frag data in regs
        __builtin_amdgcn_sched_barrier(0);
        __builtin_amdgcn_s_barrier();                        // all waves done reading
        if (t + 2 < zsteps) STAGE(t & 1, (t+2)*4);           // overwrite just-read buf
#pragma unroll
        for (int mi = 0; mi < 4; ++mi)
#pragma unroll
            for (int ni = 0; ni < 4; ++ni) {
                acc[mi][ni] = __builtin_amdgcn_mfma_f32_16x16x32_f16(Ah[mi], Bh[ni], acc[mi][ni], 0, 0, 0);
                acc[mi][ni] = __builtin_amdgcn_mfma_f32_16x16x32_f16(Ah[mi], Bl[ni], acc[mi][ni], 0, 0, 0);
                acc[mi][ni] = __builtin_amdgcn_mfma_f32_16x16x32_f16(Al[mi], Bh[ni], acc[mi][ni], 0, 0, 0);
            }
    }
#undef STAGE

    float* cb = part + ((size_t)z << 20)
              + (size_t)row0*HID + col0 + wn*64 + lr;
#pragma unroll
    for (int mi = 0; mi < 4; ++mi) {
#pragma unroll
        for (int j = 0; j < 4; ++j) {
            int row = wm*64 + mi*16 + kg*4 + j;
            float* pr = cb + (size_t)row*HID;
            pr[0]  = acc[mi][0][j];
            pr[16] = acc[mi][1][j];
            pr[32] = acc[mi][2][j];
            pr[48] = acc[mi][3][j];
        }
    }
}

// reduce fc2 partials: out32 = relu(sum_p part[p]/2048 + bias)
__global__ __launch_bounds__(256) void reduce_bias_relu(
    const float* __restrict__ part, const float* __restrict__ bias,
    float* __restrict__ out32, int nsplit)
{
    int gid = blockIdx.x*256 + threadIdx.x;
    float s = 0.f;
    for (int p = 0; p < nsplit; ++p) s += part[((size_t)p << 20) + gid];
    s = s * (1.0f/2048.0f) + bias[gid & (HID-1)];
    out32[gid] = fmaxf(s, 0.f);
}

// cls+bbox heads + decode (+softmax at last stage). 4 rows per block.
__global__ __launch_bounds__(512) void heads_kernel(
    const float* __restrict__ X, const float* __restrict__ cwT, const float* __restrict__ cb,
    const float* __restrict__ bwT, const float* __restrict__ bbb,
    float* __restrict__ cur, float* __restrict__ probs,
    const int* __restrict__ img_sz, int stage, int write_probs)
{
    __shared__ float xs[4][1024];
    __shared__ float lg[4][96];
    int tid = threadIdx.x;
    int lr = tid >> 7;           // local row 0..3
    int j  = tid & 127;
    int row0 = blockIdx.x * 4;
    for (int i = tid; i < 4096; i += 512)
        xs[i >> 10][i & 1023] = X[(size_t)(row0 + (i >> 10))*1024 + (i & 1023)];
    __syncthreads();
    int row = row0 + lr;
    if (j < 85) {
        const float* wrow = (j < 81) ? (cwT + (size_t)j*HID) : (bwT + (size_t)(j-81)*HID);
        float acc = (j < 81) ? cb[j] : bbb[j-81];
        const float4* w4 = (const float4*)wrow;
#pragma unroll 4
        for (int k4 = 0; k4 < 256; ++k4) {
            float4 wv = w4[k4];
            const float* xr = &xs[lr][k4*4];
            acc = fmaf(xr[0], wv.x, acc);
            acc = fmaf(xr[1], wv.y, acc);
            acc = fmaf(xr[2], wv.z, acc);
            acc = fmaf(xr[3], wv.w, acc);
        }
        lg[lr][j] = acc;
    }
    __syncthreads();
    if (j == 0) {   // box decode + clip
        float img = (float)(*img_sz);
        float px1 = cur[row*4+0], py1 = cur[row*4+1];
        float px2 = cur[row*4+2], py2 = cur[row*4+3];
        float pw = fmaxf(px2-px1, 1e-6f), ph = fmaxf(py2-py1, 1e-6f);
        float pcx = px1 + 0.5f*pw, pcy = py1 + 0.5f*ph;
        float wx, wy, ww, wh;
        if (stage == 0)      { wx=0.1f;   wy=0.1f;   ww=0.2f;   wh=0.2f;   }
        else if (stage == 1) { wx=0.05f;  wy=0.05f;  ww=0.1f;   wh=0.1f;   }
        else                 { wx=0.033f; wy=0.033f; ww=0.067f; wh=0.067f; }
        float dx = lg[lr][81]*wx, dy = lg[lr][82]*wy;
        float dw = fminf(lg[lr][83]*ww, CLIPV);
        float dh = fminf(lg[lr][84]*wh, CLIPV);
        float cx = dx*pw + pcx, cy = dy*ph + pcy;
        float w = expf(dw)*pw, h = expf(dh)*ph;
        cur[row*4+0] = fminf(fmaxf(cx - 0.5f*w, 0.f), img);
        cur[row*4+1] = fminf(fmaxf(cy - 0.5f*h, 0.f), img);
        cur[row*4+2] = fminf(fmaxf(cx + 0.5f*w, 0.f), img);
        cur[row*4+3] = fminf(fmaxf(cy + 0.5f*h, 0.f), img);
    }
    if (write_probs) {
        if (j == 1) {
            float m = lg[lr][0];
            for (int c2 = 1; c2 < 81; ++c2) m = fmaxf(m, lg[lr][c2]);
            float s = 0.f;
            for (int c2 = 0; c2 < 81; ++c2) s += expf(lg[lr][c2] - m);
            lg[lr][88] = m; lg[lr][89] = s;
        }
        __syncthreads();
        if (j < 81)
            probs[(size_t)row*81 + j] = expf(lg[lr][j] - lg[lr][88]) / lg[lr][89];
    }
}

// bucket passing candidates per (image,class); cross-class IoU is exactly 0.
__global__ __launch_bounds__(256) void compact_class(
    const float* __restrict__ probs, const float* __restrict__ cur,
    const int* __restrict__ img_sz, int* __restrict__ ccnt,
    float* __restrict__ ccs, float4* __restrict__ ccob, float* __restrict__ ccar,
    float4* __restrict__ ccbx, int* __restrict__ ccix)
{
    int gid = blockIdx.x*256 + threadIdx.x;
    if (gid >= NB*CAND_PER_IMG) return;
    int b = gid / CAND_PER_IMG;
    int rem = gid - b*CAND_PER_IMG;
    int n = rem / 80;
    int cm = rem - n*80;
    int label = cm + 1;
    int r = b*NPROP + n;
    float s = probs[(size_t)r*81 + label];
    float b0 = cur[r*4+0], b1 = cur[r*4+1], b2 = cur[r*4+2], b3 = cur[r*4+3];
    if (s > 0.05f && (b2 - b0) >= 1.0f && (b3 - b1) >= 1.0f) {
        int cls = b*80 + cm;
        int pos = atomicAdd(&ccnt[cls], 1);
        int base = cls*512 + pos;
        float img = (float)(*img_sz);
        float t = (float)label * (img + 2.0f);
        float o0 = b0+t, o1 = b1+t, o2 = b2+t, o3 = b3+t;
        ccs[base] = s;
        ccob[base] = make_float4(o0, o1, o2, o3);
        ccar[base] = fmaxf(o2-o0, 0.f) * fmaxf(o3-o1, 0.f);
        ccbx[base] = make_float4(b0, b1, b2, b3);
        ccix[base] = rem;   // reference flat order for tie-break
    }
}

// one wave per (image,class): greedy NMS entirely in registers
__global__ __launch_bounds__(64) void class_nms(
    const int* __restrict__ ccnt, const float* __restrict__ ccs,
    const float4* __restrict__ ccob, const float* __restrict__ ccar,
    const float4* __restrict__ ccbx, const int* __restrict__ ccix,
    float* __restrict__ svs, float4* __restrict__ svb, int* __restrict__ svi,
    int* __restrict__ svc)
{
    int cls = blockIdx.x;          // 0..159
    int Nc = ccnt[cls];
    int base = cls*512;
    int lane = threadIdx.x;
    __shared__ float sel[5];
    float s[8]; float4 ob[8]; float a[8]; int ix[8];
    int cntl = 0;
    for (int j = lane; j < Nc; j += 64) {
        s[cntl] = ccs[base+j]; ob[cntl] = ccob[base+j];
        a[cntl] = ccar[base+j]; ix[cntl] = ccix[base+j];
        ++cntl;
    }
    int svn = 0;
    int rounds = (Nc < 100) ? Nc : 100;
    for (int it = 0; it < rounds; ++it) {
        float bs = -1.f; int bi = 0x7fffffff;
        for (int q = 0; q < cntl; ++q)
            if (s[q] > bs || (s[q] == bs && ix[q] < bi)) { bs = s[q]; bi = ix[q]; }
        for (int off = 32; off > 0; off >>= 1) {
            float os = __shfl_xor(bs, off);
            int oi = __shfl_xor(bi, off);
            if (os > bs || (os == bs && oi < bi)) { bs = os; bi = oi; }
        }
        if (bs <= 0.f) break;      // uniform across wave
        for (int q = 0; q < cntl; ++q) {
            if (s[q] == bs && ix[q] == bi) {   // unique owner (ix unique)
                sel[0] = ob[q].x; sel[1] = ob[q].y; sel[2] = ob[q].z; sel[3] = ob[q].w;
                sel[4] = a[q];
                int slot = cls*128 + svn;
                svs[slot] = bs;
                svb[slot] = ccbx[base + lane + q*64];
                svi[slot] = bi;
                s[q] = -1.f;
            }
        }
        __syncthreads();
        float bi0 = sel[0], bi1 = sel[1], bi2 = sel[2], bi3 = sel[3], ai = sel[4];
        for (int q = 0; q < cntl; ++q) {
            if (s[q] > 0.f) {
                float ix1 = fmaxf(bi0, ob[q].x), iy1 = fmaxf(bi1, ob[q].y);
                float ix2 = fminf(bi2, ob[q].z), iy2 = fminf(bi3, ob[q].w);
                float inter = fmaxf(ix2-ix1, 0.f) * fmaxf(iy2-iy1, 0.f);
                float iou = inter / (ai + a[q] - inter + 1e-9f);
                if (iou > 0.5f) s[q] = -1.f;
            }
        }
        ++svn;
        __syncthreads();
    }
    if (lane == 0) svc[cls] = svn;
}

// per image: bitonic-sort survivors by (score desc, coidx asc), write top-100.
__global__ __launch_bounds__(256) void merge_topk(
    const float* __restrict__ svs, const float4* __restrict__ svb,
    const int* __restrict__ svi, const int* __restrict__ svc,
    float* __restrict__ out)
{
    extern __shared__ char smem[];
    u64* keys = (u64*)smem;                 // [8192] 64KB
    u32* pay  = (u32*)(smem + 65536);       // [8192] 32KB
    __shared__ int off[81];
    __shared__ int n2s;
    int b = blockIdx.x, tid = threadIdx.x;
    if (tid == 0) {
        int run = 0;
        for (int c = 0; c < 80; ++c) { off[c] = run; run += svc[b*80 + c]; }
        off[80] = run;
        int n2 = 256;
        while (n2 < run) n2 <<= 1;
        n2s = n2;
    }
    __syncthreads();
    int Ns = off[80], n2 = n2s;
    for (int c = 0; c < 80; ++c) {
        int n = off[c+1] - off[c];
        int srcb = (b*80 + c)*128;
        for (int k = tid; k < n; k += 256) {
            int src = srcb + k;
            keys[off[c] + k] = ((u64)__float_as_uint(svs[src]) << 32)
                             | (u64)(0xFFFFFFFFu - (u32)svi[src]);
            pay[off[c] + k] = src;
        }
    }
    for (int i = Ns + tid; i < n2; i += 256) { keys[i] = 0; pay[i] = 0; }
    __syncthreads();
    for (int k = 2; k <= n2; k <<= 1) {
        for (int j = k >> 1; j > 0; j >>= 1) {
            for (int i = tid; i < n2; i += 256) {
                int l = i ^ j;
                if (l > i) {
                    u64 a = keys[i], bb = keys[l];
                    bool dir = ((i & k) == 0);
                    if ((a < bb) == dir) {
                        keys[i] = bb; keys[l] = a;
                        u32 p = pay[i]; pay[i] = pay[l]; pay[l] = p;
                    }
                }
            }
            __syncthreads();
        }
    }
    if (tid < 100) {
        u64 kk = keys[tid];      // n2 >= 256 > 100 always
        if (kk != 0) {
            u32 ci = 0xFFFFFFFFu - (u32)(kk & 0xFFFFFFFFull);
            float4 bx = svb[pay[tid]];
            out[b*400 + tid*4 + 0] = bx.x;
            out[b*400 + tid*4 + 1] = bx.y;
            out[b*400 + tid*4 + 2] = bx.z;
            out[b*400 + tid*4 + 3] = bx.w;
            out[800  + b*100 + tid] = __uint_as_float((u32)(kk >> 32));
            out[1000 + b*100 + tid] = (float)((ci % 80) + 1);
        } else {
            out[b*400 + tid*4 + 0] = 0.f; out[b*400 + tid*4 + 1] = 0.f;
            out[b*400 + tid*4 + 2] = 0.f; out[b*400 + tid*4 + 3] = 0.f;
            out[800  + b*100 + tid] = 0.f;
            out[1000 + b*100 + tid] = 0.f;
        }
    }
}

extern "C" void kernel_launch(void* const* d_in, const int* in_sizes, int n_in,
                              void* d_out, int out_size, void* d_ws, size_t ws_size,
                              hipStream_t stream)
{
    const float* features  = (const float*)d_in[0];
    const float* proposals = (const float*)d_in[1];
    const float* fc1_w = (const float*)d_in[2];
    const float* fc1_b = (const float*)d_in[3];
    const float* fc2_w = (const float*)d_in[4];
    const float* fc2_b = (const float*)d_in[5];
    const float* cls_w = (const float*)d_in[6];
    const float* cls_b = (const float*)d_in[7];
    const float* bbox_w = (const float*)d_in[8];
    const float* bbox_b = (const float*)d_in[9];
    const int* img_sz = (const int*)d_in[10];
    float* out = (float*)d_out;
    char* ws = (char*)d_ws;
    _Float16* xhi   = (_Float16*)(ws + XHI_OFF);
    _Float16* xlo   = (_Float16*)(ws + XLO_OFF);
    _Float16* wt1hi = (_Float16*)(ws + WT1HI_OFF);
    _Float16* wt1lo = (_Float16*)(ws + WT1LO_OFF);
    _Float16* wt2hi = (_Float16*)(ws + WT2HI_OFF);
    _Float16* wt2lo = (_Float16*)(ws + WT2LO_OFF);
    _Float16* h1hi  = (_Float16*)(ws + H1HI_OFF);
    _Float16* h1lo  = (_Float16*)(ws + H1LO_OFF);
    float*  h2     = (float*) (ws + H2_OFF);
    float*  cwT    = (float*) (ws + CWT_OFF);
    float*  bwT    = (float*) (ws + BWT_OFF);
    float*  probs  = (float*) (ws + PROBS_OFF);
    float*  cur    = (float*) (ws + CUR_OFF);
    int*    ccnt   = (int*)   (ws + CNT_OFF);
    float*  ccs    = (float*) (ws + CCS_OFF);
    float4* ccob   = (float4*)(ws + CCOB_OFF);
    float*  ccar   = (float*) (ws + CCAR_OFF);
    float4* ccbx   = (float4*)(ws + CCBX_OFF);
    int*    ccix   = (int*)   (ws + CCIX_OFF);
    float*  svs    = (float*) (ws + SVS_OFF);
    float4* svb    = (float4*)(ws + SVB_OFF);
    int*    svi    = (int*)   (ws + SVI_OFF);
    int*    svc    = (int*)   (ws + SVC_OFF);
    float*  part   = (float*) (ws + PART_OFF);

    prep_kernel<<<1020, 256, 0, stream>>>(cls_w, bbox_w, cwT, bwT, ccnt);
    hipMemcpyAsync(cur, proposals, (size_t)NROWS*4*sizeof(float),
                   hipMemcpyDeviceToDevice, stream);

    for (int st = 0; st < 3; ++st) {
        // roi_align || fc1-weight limb transpose (independent)
        roi_tl1_kernel<<<256 + 12544, 256, 0, stream>>>(
            features, cur, xhi, xlo,
            fc1_w + (size_t)st*INDIM*HID, wt1hi, wt1lo);
        // fc1: 392 K-steps; z=16 (8 x 25 + 8 x 24); 256 blocks = 1/CU
        mfma_gemm_limb256<<<256, 512, 131072, stream>>>(
            xhi, xlo, wt1hi, wt1lo, part, 24, 8);
        // reduce fc1 partials -> h1 limbs || fc2-weight limb transpose
        red1_tl2_kernel<<<4096 + 1024, 256, 0, stream>>>(
            part, fc1_b + st*HID, h1hi, h1lo,
            fc2_w + (size_t)st*HID*HID, wt2hi, wt2lo);
        // fc2: K=1024 = 32 K-steps; z=8 x 4 steps
        mfma_gemm_limb<<<512, 256, 0, stream>>>(
            h1hi, h1lo, wt2hi, wt2lo, part, 4, 0, 3);
        reduce_bias_relu<<<4096, 256, 0, stream>>>(
            part, fc2_b + st*HID, h2, 8);
        heads_kernel<<<NROWS/4, 512, 0, stream>>>(
            h2, cwT + (size_t)st*NCLS*HID, cls_b + st*NCLS,
            bwT + (size_t)st*4*HID, bbox_b + st*4,
            cur, probs, img_sz, st, st == 2 ? 1 : 0);
    }
    compact_class<<<(NB*CAND_PER_IMG)/256, 256, 0, stream>>>(
        probs, cur, img_sz, ccnt, ccs, ccob, ccar, ccbx, ccix);
    class_nms<<<160, 64, 0, stream>>>(
        ccnt, ccs, ccob, ccar, ccbx, ccix, svs, svb, svi, svc);
    merge_topk<<<NB, 256, 98304, stream>>>(
        svs, svb, svi, svc, out);
}

// Round 13
// 655.701 us; speedup vs baseline: 1.1914x; 1.0591x over previous
//
#include <hip/hip_runtime.h>
#include <math.h>

#define NPROP 512
#define NB 2
#define NROWS (NB*NPROP)          // 1024
#define FCH 256
#define FH 64
#define FW 64
#define INDIM (FCH*7*7)           // 12544
#define HID 1024
#define NCLS 81
#define CAND_PER_IMG (NPROP*(NCLS-1))  // 40960
#define CLIPV 4.1351666f          // log(1000/16) rounded to f32
#define RCH 896                   // 12544 = 14 * 896; 112 octets/chunk
#define NCHUNK 14
#define BSTRIDE 904               // padded LDS row (452 dwords, %32=4: no 4-way conflict)

typedef _Float16 f16x8 __attribute__((ext_vector_type(8)));
typedef float f32x4 __attribute__((ext_vector_type(4)));
typedef unsigned int u32;
typedef unsigned long long u64;

__device__ __forceinline__ void gload16(const void* g, void* l) {
    __builtin_amdgcn_global_load_lds((const __attribute__((address_space(1))) u32*)g,
                                     (__attribute__((address_space(3))) u32*)l, 16, 0, 0);
}

// Limb planes are k-octet-major: [K/8][1024][8] f16. Octet stride = 8192 elems.

// ---- workspace layout (bytes) ----
#define XHI_OFF    0ull
#define XLO_OFF    25690112ull
#define WT1HI_OFF  51380224ull
#define WT1LO_OFF  77070336ull
#define WT2HI_OFF  102760448ull
#define WT2LO_OFF  104857600ull
#define H1HI_OFF   106954752ull
#define H1LO_OFF   109051904ull
#define H2_OFF     111149056ull
#define CWT_OFF    115343360ull
#define BWT_OFF    116338688ull
#define PROBS_OFF  116387840ull
#define CUR_OFF    116719616ull
#define CNT_OFF    116736000ull   // ccnt[160] ints
#define CCS_OFF    116737024ull   // per-class scores   [160][512] f32
#define CCOB_OFF   117064704ull   // per-class off-box  [160][512] float4
#define CCAR_OFF   118375424ull   // per-class area     [160][512] f32
#define CCBX_OFF   118703104ull   // per-class box      [160][512] float4
#define CCIX_OFF   120013824ull   // per-class coidx    [160][512] int
#define SVS_OFF    120341504ull   // survivors score    [160][128] f32
#define SVB_OFF    120423424ull   // survivors box      [160][128] float4
#define SVI_OFF    120751104ull   // survivors coidx    [160][128] int
#define SVC_OFF    120833024ull   // survivor count     [160] int
#define PART_OFF   121489408ull   // 16 planes of 1024x1024 f32 = 67 MB

// prep: head-weight transposes (cls+bbox, all stages) + ccnt init. grid 1020.
__global__ __launch_bounds__(256) void prep_kernel(
    const float* __restrict__ cls_w, const float* __restrict__ bbox_w,
    float* __restrict__ cwT, float* __restrict__ bwT, int* __restrict__ ccnt)
{
    int bid = blockIdx.x, tid = threadIdx.x;
    if (bid == 0 && tid < 160) ccnt[tid] = 0;
    int gid = bid*256 + tid;
    if (gid < 3*NCLS*HID) {            // cls: [3][1024][81] -> [3][81][1024]
        int per = NCLS*HID;
        int b = gid / per, rem = gid - b*per;
        int n = rem / HID, k = rem - n*HID;
        cwT[gid] = cls_w[(size_t)b*per + (size_t)k*NCLS + n];
    } else {
        int g2 = gid - 3*NCLS*HID;     // bbox: [3][1024][4] -> [3][4][1024]
        int per = 4*HID;
        int b = g2 / per, rem = g2 - b*per;
        int n = rem / HID, k = rem - n*HID;
        bwT[g2] = bbox_w[(size_t)b*per + (size_t)k*4 + n];
    }
}

// ---------------------------------------------------------------------------
// FUSED: roi_align chunk-parallel (blocks 0..3583: one (quad,chunk) each)
//     || trans_limb fc1_w (blocks 3584..16127).
// Chunk-split raises roi occupancy 4 -> 28 waves/CU (was latency-bound at
// 1 block/CU after tl1 blocks drained). LDS 20.7KB -> 7 blocks/CU.
// ---------------------------------------------------------------------------
__global__ __launch_bounds__(256) void roi_tl1_kernel(
    const float* __restrict__ feat, const float* __restrict__ boxes,
    _Float16* __restrict__ Xhi, _Float16* __restrict__ Xlo,
    const float* __restrict__ w_in, _Float16* __restrict__ whi, _Float16* __restrict__ wlo)
{
    __shared__ __align__(16) char sh[20736];
    const int tid = threadIdx.x;
    const int bid = blockIdx.x;

    if (bid < 256*NCHUNK) {
        _Float16* bufh = (_Float16*)sh;                // [4][BSTRIDE]
        _Float16* bufl = (_Float16*)(sh + 7232);
        int*   sidx = (int*)(sh + 14464);              // [4][4][49]
        float* swt  = (float*)(sh + 17600);
        const int w = tid >> 6, lane = tid & 63;
        const int quad = bid & 255, ch = bid >> 8;     // ch 0..13
        const int r0 = quad << 2;
        const int r = r0 + w;
        const int b = r >> 9;
        const float* f = feat + (size_t)b * (FCH*FH*FW);
        if (lane < 49) {
            float x1 = boxes[r*4+0]*0.125f, y1 = boxes[r*4+1]*0.125f;
            float x2 = boxes[r*4+2]*0.125f, y2 = boxes[r*4+3]*0.125f;
            float bw = fmaxf(x2-x1, 1.0f) / 7.0f;
            float bh = fmaxf(y2-y1, 1.0f) / 7.0f;
            int py = lane / 7, px = lane - py*7;
            float gx = x1 + ((float)px + 0.5f)*bw;
            float gy = y1 + ((float)py + 0.5f)*bh;
            gx = fminf(fmaxf(gx, 0.0f), 63.0f);
            gy = fminf(fmaxf(gy, 0.0f), 63.0f);
            float x0f = floorf(gx), y0f = floorf(gy);
            int x0 = (int)x0f, y0 = (int)y0f;
            int x1c = min(x0+1, 63), y1c = min(y0+1, 63);
            float dx = gx - x0f, dy = gy - y0f;
            sidx[(w*4+0)*49 + lane] = y0*FW + x0;
            sidx[(w*4+1)*49 + lane] = y0*FW + x1c;
            sidx[(w*4+2)*49 + lane] = y1c*FW + x0;
            sidx[(w*4+3)*49 + lane] = y1c*FW + x1c;
            swt[(w*4+0)*49 + lane] = (1.0f-dy)*(1.0f-dx);
            swt[(w*4+1)*49 + lane] = (1.0f-dy)*dx;
            swt[(w*4+2)*49 + lane] = dy*(1.0f-dx);
            swt[(w*4+3)*49 + lane] = dy*dx;
        }
        __syncthreads();
        for (int i2 = lane; i2 < RCH; i2 += 64) {
            int i = ch*RCH + i2;
            int c = i / 49;
            int p = i - c*49;
            const float* fc = f + c*(FH*FW);
            float v = fc[sidx[(w*4+0)*49+p]]*swt[(w*4+0)*49+p]
                    + fc[sidx[(w*4+1)*49+p]]*swt[(w*4+1)*49+p]
                    + fc[sidx[(w*4+2)*49+p]]*swt[(w*4+2)*49+p]
                    + fc[sidx[(w*4+3)*49+p]]*swt[(w*4+3)*49+p];
            float vs = v * 32.0f;
            _Float16 h = (_Float16)vs;
            bufh[w*BSTRIDE + i2] = h;
            bufl[w*BSTRIDE + i2] = (_Float16)(vs - (float)h);
        }
        __syncthreads();
        // write-out: q = (oct<<2)|p; consecutive lanes -> 64B contiguous runs
        for (int q = tid; q < 112*4; q += 256) {
            int oct = q >> 2, p = q & 3;
            f16x8 hv = *(const f16x8*)&bufh[p*BSTRIDE + oct*8];
            f16x8 lv = *(const f16x8*)&bufl[p*BSTRIDE + oct*8];
            size_t idx = ((size_t)(ch*112 + oct) << 13) + ((size_t)(r0 + p) << 3);
            *(f16x8*)(Xhi + idx) = hv;
            *(f16x8*)(Xlo + idx) = lv;
        }
    } else {
        // ---- trans_limb fc1_w: [12544][1024] -> octet-major limbs ----
        float (*t)[33] = (float(*)[33])sh;             // 4224B, aliases roi bufs
        const int bid2 = bid - 256*NCHUNK;
        const int tx = tid & 31, ty = tid >> 5;
        const int n0 = (bid2 & 31) << 5, k0 = (bid2 >> 5) << 5;
#pragma unroll
        for (int r = 0; r < 4; ++r)
            t[ty + 8*r][tx] = w_in[(size_t)(k0 + ty + 8*r)*HID + n0 + tx];
        __syncthreads();
        if (ty < 4) {
            int n = n0 + tx;
            f16x8 hv, lv;
#pragma unroll
            for (int e = 0; e < 8; ++e) {
                float v = t[ty*8 + e][tx] * 64.0f;
                _Float16 h = (_Float16)v;
                hv[e] = h;
                lv[e] = (_Float16)(v - (float)h);
            }
            size_t idx = (((size_t)(k0 >> 3) + ty)*HID << 3) + ((size_t)n << 3);
            *(f16x8*)(whi + idx) = hv;
            *(f16x8*)(wlo + idx) = lv;
        }
    }
}

// ---------------------------------------------------------------------------
// FUSED: reduce1 (blocks 0..4095, h1 limbs) || trans_limb fc2_w (4096..5119).
// ---------------------------------------------------------------------------
__global__ __launch_bounds__(256) void red1_tl2_kernel(
    const float* __restrict__ part, const float* __restrict__ bias,
    _Float16* __restrict__ outhi, _Float16* __restrict__ outlo,
    const float* __restrict__ w_in, _Float16* __restrict__ whi, _Float16* __restrict__ wlo)
{
    __shared__ float t[32][33];
    const int tid = threadIdx.x;
    const int bid = blockIdx.x;
    if (bid < 4096) {
        int gid = bid*256 + tid;
        float s = 0.f;
        for (int p = 0; p < 16; ++p) s += part[((size_t)p << 20) + gid];
        s = s * (1.0f/2048.0f) + bias[gid & (HID-1)];
        s = fmaxf(s, 0.f);
        float vs = s * 32.0f;
        _Float16 h = (_Float16)vs;
        int row = gid >> 10, col = gid & 1023;
        size_t idx = ((size_t)(col >> 3) << 13) + ((size_t)row << 3) + (col & 7);
        outhi[idx] = h;
        outlo[idx] = (_Float16)(vs - (float)h);
    } else {
        const int bid2 = bid - 4096;
        const int tx = tid & 31, ty = tid >> 5;
        const int n0 = (bid2 & 31) << 5, k0 = (bid2 >> 5) << 5;
#pragma unroll
        for (int r = 0; r < 4; ++r)
            t[ty + 8*r][tx] = w_in[(size_t)(k0 + ty + 8*r)*HID + n0 + tx];
        __syncthreads();
        if (ty < 4) {
            int n = n0 + tx;
            f16x8 hv, lv;
#pragma unroll
            for (int e = 0; e < 8; ++e) {
                float v = t[ty*8 + e][tx] * 64.0f;
                _Float16 h = (_Float16)v;
                hv[e] = h;
                lv[e] = (_Float16)(v - (float)h);
            }
            size_t idx = (((size_t)(k0 >> 3) + ty)*HID << 3) + ((size_t)n << 3);
            *(f16x8*)(whi + idx) = hv;
            *(f16x8*)(wlo + idx) = lv;
        }
    }
}

// ---------------------------------------------------------------------------
// fc1 GEMM: 256x256 tile, 8 waves (2x4), f16-limb MFMA, 128KB dynamic-LDS
// double buffer, counted vmcnt(8), coalesced k-octet-major staging.
// lgkmcnt drain + sched_barrier(0) before second barrier (rule #18 race fix).
// ---------------------------------------------------------------------------
__global__ __launch_bounds__(512, 2) void mfma_gemm_limb256(
    const _Float16* __restrict__ Ahi, const _Float16* __restrict__ Alo,
    const _Float16* __restrict__ Bhi, const _Float16* __restrict__ Blo,
    float* __restrict__ part, int base, int extra)
{
    extern __shared__ __align__(16) char ldsraw[];   // 131072 bytes
    const int tid = threadIdx.x;
    const int lane = tid & 63;
    const int w = tid >> 6;            // 0..7
    const int wm = w >> 2, wn = w & 3; // wave tile: rows wm*128, cols wn*64
    const int kg = lane >> 4, lr = lane & 15;
    const int bid = blockIdx.x;
    const int z = bid & 15;
    const int tile = bid >> 4;
    const int bx = tile & 3, by = tile >> 2;
    const int row0 = by << 8, col0 = bx << 8;
    const int zsteps = base + (z < extra ? 1 : 0);
    const int o0 = ((z*base + (z < extra ? z : extra)) * 32) >> 3;  // start octet

    const int sp = w >> 1;
    const int sbase = (w & 1) * 8;
    const _Float16* pl = (sp == 0) ? Ahi : (sp == 1) ? Alo : (sp == 2) ? Bhi : Blo;
    const int rc0 = (sp < 2) ? row0 : col0;
    const _Float16* sG = pl + ((size_t)(rc0 + lane) << 3);   // per-lane, coalesced

    f32x4 acc[8][4];
#pragma unroll
    for (int i = 0; i < 8; ++i)
#pragma unroll
        for (int j = 0; j < 4; ++j) acc[i][j] = (f32x4){0.f, 0.f, 0.f, 0.f};

    auto STAGE = [&](int bufoff, int koct) {
#pragma unroll
        for (int j = 0; j < 8; ++j) {
            int sub = sbase + j;           // 0..15: ks = sub>>2, rblk = sub&3
            int ks = sub >> 2, rblk = sub & 3;
            const void* g = (const void*)(sG + ((size_t)(o0 + koct + ks) << 13)
                                             + ((size_t)rblk << 9));
            void* l = (void*)(ldsraw + bufoff + sp*16384 + ks*4096 + rblk*1024);
            gload16(g, l);                 // dest uniform; HW adds lane*16
        }
    };

    STAGE(0, 0);
    if (zsteps > 1) STAGE(65536, 4);

    for (int t = 0; t < zsteps; ++t) {
        if (t + 1 < zsteps) asm volatile("s_waitcnt vmcnt(8)" ::: "memory");
        else                asm volatile("s_waitcnt vmcnt(0)" ::: "memory");
        __builtin_amdgcn_s_barrier();          // all waves' stage of tile t done
        asm volatile("" ::: "memory");
        const char* Lb = ldsraw + ((t & 1) ? 65536 : 0);
        f16x8 Bh[4], Bl[4];
#pragma unroll
        for (int ni = 0; ni < 4; ++ni) {
            int s = (kg*256 + wn*64 + ni*16 + lr) * 16;
            Bh[ni] = *(const f16x8*)(Lb + 2*16384 + s);
            Bl[ni] = *(const f16x8*)(Lb + 3*16384 + s);
        }
#pragma unroll
        for (int mi = 0; mi < 8; ++mi) {       // A reads fused under MFMA
            int s = (kg*256 + wm*128 + mi*16 + lr) * 16;
            f16x8 ah = *(const f16x8*)(Lb + s);
            f16x8 al = *(const f16x8*)(Lb + 16384 + s);
#pragma unroll
            for (int ni = 0; ni < 4; ++ni) {
                acc[mi][ni] = __builtin_amdgcn_mfma_f32_16x16x32_f16(ah, Bh[ni], acc[mi][ni], 0, 0, 0);
                acc[mi][ni] = __builtin_amdgcn_mfma_f32_16x16x32_f16(ah, Bl[ni], acc[mi][ni], 0, 0, 0);
                acc[mi][ni] = __builtin_amdgcn_mfma_f32_16x16x32_f16(al, Bh[ni], acc[mi][ni], 0, 0, 0);
            }
        }
        // RACE FIX (rule #18): drain LDS reads, pin order, then barrier.
        asm volatile("s_waitcnt lgkmcnt(0)" ::: "memory");
        __builtin_amdgcn_sched_barrier(0);
        __builtin_amdgcn_s_barrier();          // all waves done reading buf
        asm volatile("" ::: "memory");
        if (t + 2 < zsteps) STAGE((t & 1) ? 65536 : 0, (t+2)*4);
    }

    // epilogue: C/D layout col=lane&15, row=(lane>>4)*4+j
    float* cb = part + ((size_t)z << 20)
              + (size_t)row0*HID + col0 + wn*64 + lr;
#pragma unroll
    for (int mi = 0; mi < 8; ++mi) {
#pragma unroll
        for (int j = 0; j < 4; ++j) {
            int row = wm*128 + mi*16 + kg*4 + j;
            float* pr = cb + (size_t)row*HID;
            pr[0]  = acc[mi][0][j];
            pr[16] = acc[mi][1][j];
            pr[32] = acc[mi][2][j];
            pr[48] = acc[mi][3][j];
        }
    }
}

// ---------------------------------------------------------------------------
// fc2 GEMM: 128x128 tile, depth-2 dbuf, counted vmcnt; coalesced staging.
// ---------------------------------------------------------------------------
__global__ __launch_bounds__(256) void mfma_gemm_limb(
    const _Float16* __restrict__ Ahi, const _Float16* __restrict__ Alo,
    const _Float16* __restrict__ Bhi, const _Float16* __restrict__ Blo,
    float* __restrict__ part, int base, int extra, int lognz)
{
    __shared__ __align__(16) _Float16 lds[2][4][512][8];   // 2 x 32KB
    const int tid = threadIdx.x;
    const int lane = tid & 63;
    const int w = tid >> 6, wm = w >> 1, wn = w & 1;
    const int kg = lane >> 4, lr = lane & 15;
    const int bid = blockIdx.x;
    const int nzm = (1 << lognz) - 1;
    const int z = bid & nzm;
    const int bx = (bid >> lognz) & 7;
    const int by = bid >> (lognz + 3);
    const int row0 = by << 7, col0 = bx << 7;
    const int zsteps = base + (z < extra ? 1 : 0);
    const int o0 = ((z*base + (z < extra ? z : extra)) * 32) >> 3;
    const int r_ = tid & 127;
    const int ks1 = tid >> 7;          // 0 or 1
    const int wb = tid & 192;          // wave-uniform slot base

    const _Float16* srcA0 = Ahi + ((size_t)(row0 + r_) << 3);
    const _Float16* srcA1 = Alo + ((size_t)(row0 + r_) << 3);
    const _Float16* srcB0 = Bhi + ((size_t)(col0 + r_) << 3);
    const _Float16* srcB1 = Blo + ((size_t)(col0 + r_) << 3);

    f32x4 acc[4][4];
#pragma unroll
    for (int i = 0; i < 4; ++i)
#pragma unroll
        for (int j = 0; j < 4; ++j) acc[i][j] = (f32x4){0.f, 0.f, 0.f, 0.f};

#define STAGE(bf, oct) do { \
    _Float16* Lb = &lds[bf][0][0][0]; \
    gload16(srcA0 + ((size_t)(o0+(oct)+ks1  ) << 13), (void*)(Lb + (0*512 +       wb)*8)); \
    gload16(srcA0 + ((size_t)(o0+(oct)+ks1+2) << 13), (void*)(Lb + (0*512 + 256 + wb)*8)); \
    gload16(srcA1 + ((size_t)(o0+(oct)+ks1  ) << 13), (void*)(Lb + (1*512 +       wb)*8)); \
    gload16(srcA1 + ((size_t)(o0+(oct)+ks1+2) << 13), (void*)(Lb + (1*512 + 256 + wb)*8)); \
    gload16(srcB0 + ((size_t)(o0+(oct)+ks1  ) << 13), (void*)(Lb + (2*512 +       wb)*8)); \
    gload16(srcB0 + ((size_t)(o0+(oct)+ks1+2) << 13), (void*)(Lb + (2*512 + 256 + wb)*8)); \
    gload16(srcB1 + ((size_t)(o0+(oct)+ks1  ) << 13), (void*)(Lb + (3*512 +       wb)*8)); \
    gload16(srcB1 + ((size_t)(o0+(oct)+ks1+2) << 13), (void*)(Lb + (3*512 + 256 + wb)*8)); \
} while (0)

    STAGE(0, 0);
    if (1 < zsteps) STAGE(1, 4);
    for (int t = 0; t < zsteps; ++t) {
        if (t + 1 < zsteps) asm volatile("s_waitcnt vmcnt(8)" ::: "memory");
        else                asm volatile("s_waitcnt vmcnt(0)" ::: "memory");
        __builtin_amdgcn_s_barrier();
        const _Float16* Lr = &lds[t & 1][0][0][0];
        f16x8 Ah[4], Al[4], Bh[4], Bl[4];
#pragma unroll
        for (int mi = 0; mi < 4; ++mi) {
            int s = kg*128 + wm*64 + mi*16 + lr;
            Ah[mi] = *(const f16x8*)(Lr + (0*512 + s)*8);
            Al[mi] = *(const f16x8*)(Lr + (1*512 + s)*8);
        }
#pragma unroll
        for (int ni = 0; ni < 4; ++ni) {
            int s = kg*128 + wn*64 + ni*16 + lr;
            Bh[ni] = *(const f16x8*)(Lr + (2*512 + s)*8);
            Bl[ni] = *(const f16x8*)(Lr + (3*512 + s)*8);
        }
        asm volatile("s_waitcnt lgkmcnt(0)" ::: "memory");   // frag data in regs
        __builtin_amdgcn_sched_barrier(0);
        __builtin_amdgcn_s_barrier();                        // all waves done reading
        if (t + 2 < zsteps) STAGE(t & 1, (t+2)*4);           // overwrite just-read buf
#pragma unroll
        for (int mi = 0; mi < 4; ++mi)
#pragma unroll
            for (int ni = 0; ni < 4; ++ni) {
                acc[mi][ni] = __builtin_amdgcn_mfma_f32_16x16x32_f16(Ah[mi], Bh[ni], acc[mi][ni], 0, 0, 0);
                acc[mi][ni] = __builtin_amdgcn_mfma_f32_16x16x32_f16(Ah[mi], Bl[ni], acc[mi][ni], 0, 0, 0);
                acc[mi][ni] = __builtin_amdgcn_mfma_f32_16x16x32_f16(Al[mi], Bh[ni], acc[mi][ni], 0, 0, 0);
            }
    }
#undef STAGE

    float* cb = part + ((size_t)z << 20)
              + (size_t)row0*HID + col0 + wn*64 + lr;
#pragma unroll
    for (int mi = 0; mi < 4; ++mi) {
#pragma unroll
        for (int j = 0; j < 4; ++j) {
            int row = wm*64 + mi*16 + kg*4 + j;
            float* pr = cb + (size_t)row*HID;
            pr[0]  = acc[mi][0][j];
            pr[16] = acc[mi][1][j];
            pr[32] = acc[mi][2][j];
            pr[48] = acc[mi][3][j];
        }
    }
}

// reduce fc2 partials: out32 = relu(sum_p part[p]/2048 + bias)
__global__ __launch_bounds__(256) void reduce_bias_relu(
    const float* __restrict__ part, const float* __restrict__ bias,
    float* __restrict__ out32, int nsplit)
{
    int gid = blockIdx.x*256 + threadIdx.x;
    float s = 0.f;
    for (int p = 0; p < nsplit; ++p) s += part[((size_t)p << 20) + gid];
    s = s * (1.0f/2048.0f) + bias[gid & (HID-1)];
    out32[gid] = fmaxf(s, 0.f);
}

// cls+bbox heads + decode (+softmax at last stage). 4 rows per block.
__global__ __launch_bounds__(512) void heads_kernel(
    const float* __restrict__ X, const float* __restrict__ cwT, const float* __restrict__ cb,
    const float* __restrict__ bwT, const float* __restrict__ bbb,
    float* __restrict__ cur, float* __restrict__ probs,
    const int* __restrict__ img_sz, int stage, int write_probs)
{
    __shared__ float xs[4][1024];
    __shared__ float lg[4][96];
    int tid = threadIdx.x;
    int lr = tid >> 7;           // local row 0..3
    int j  = tid & 127;
    int row0 = blockIdx.x * 4;
    for (int i = tid; i < 4096; i += 512)
        xs[i >> 10][i & 1023] = X[(size_t)(row0 + (i >> 10))*1024 + (i & 1023)];
    __syncthreads();
    int row = row0 + lr;
    if (j < 85) {
        const float* wrow = (j < 81) ? (cwT + (size_t)j*HID) : (bwT + (size_t)(j-81)*HID);
        float acc = (j < 81) ? cb[j] : bbb[j-81];
        const float4* w4 = (const float4*)wrow;
#pragma unroll 4
        for (int k4 = 0; k4 < 256; ++k4) {
            float4 wv = w4[k4];
            const float* xr = &xs[lr][k4*4];
            acc = fmaf(xr[0], wv.x, acc);
            acc = fmaf(xr[1], wv.y, acc);
            acc = fmaf(xr[2], wv.z, acc);
            acc = fmaf(xr[3], wv.w, acc);
        }
        lg[lr][j] = acc;
    }
    __syncthreads();
    if (j == 0) {   // box decode + clip
        float img = (float)(*img_sz);
        float px1 = cur[row*4+0], py1 = cur[row*4+1];
        float px2 = cur[row*4+2], py2 = cur[row*4+3];
        float pw = fmaxf(px2-px1, 1e-6f), ph = fmaxf(py2-py1, 1e-6f);
        float pcx = px1 + 0.5f*pw, pcy = py1 + 0.5f*ph;
        float wx, wy, ww, wh;
        if (stage == 0)      { wx=0.1f;   wy=0.1f;   ww=0.2f;   wh=0.2f;   }
        else if (stage == 1) { wx=0.05f;  wy=0.05f;  ww=0.1f;   wh=0.1f;   }
        else                 { wx=0.033f; wy=0.033f; ww=0.067f; wh=0.067f; }
        float dx = lg[lr][81]*wx, dy = lg[lr][82]*wy;
        float dw = fminf(lg[lr][83]*ww, CLIPV);
        float dh = fminf(lg[lr][84]*wh, CLIPV);
        float cx = dx*pw + pcx, cy = dy*ph + pcy;
        float w = expf(dw)*pw, h = expf(dh)*ph;
        cur[row*4+0] = fminf(fmaxf(cx - 0.5f*w, 0.f), img);
        cur[row*4+1] = fminf(fmaxf(cy - 0.5f*h, 0.f), img);
        cur[row*4+2] = fminf(fmaxf(cx + 0.5f*w, 0.f), img);
        cur[row*4+3] = fminf(fmaxf(cy + 0.5f*h, 0.f), img);
    }
    if (write_probs) {
        if (j == 1) {
            float m = lg[lr][0];
            for (int c2 = 1; c2 < 81; ++c2) m = fmaxf(m, lg[lr][c2]);
            float s = 0.f;
            for (int c2 = 0; c2 < 81; ++c2) s += expf(lg[lr][c2] - m);
            lg[lr][88] = m; lg[lr][89] = s;
        }
        __syncthreads();
        if (j < 81)
            probs[(size_t)row*81 + j] = expf(lg[lr][j] - lg[lr][88]) / lg[lr][89];
    }
}

// bucket passing candidates per (image,class); cross-class IoU is exactly 0.
__global__ __launch_bounds__(256) void compact_class(
    const float* __restrict__ probs, const float* __restrict__ cur,
    const int* __restrict__ img_sz, int* __restrict__ ccnt,
    float* __restrict__ ccs, float4* __restrict__ ccob, float* __restrict__ ccar,
    float4* __restrict__ ccbx, int* __restrict__ ccix)
{
    int gid = blockIdx.x*256 + threadIdx.x;
    if (gid >= NB*CAND_PER_IMG) return;
    int b = gid / CAND_PER_IMG;
    int rem = gid - b*CAND_PER_IMG;
    int n = rem / 80;
    int cm = rem - n*80;
    int label = cm + 1;
    int r = b*NPROP + n;
    float s = probs[(size_t)r*81 + label];
    float b0 = cur[r*4+0], b1 = cur[r*4+1], b2 = cur[r*4+2], b3 = cur[r*4+3];
    if (s > 0.05f && (b2 - b0) >= 1.0f && (b3 - b1) >= 1.0f) {
        int cls = b*80 + cm;
        int pos = atomicAdd(&ccnt[cls], 1);
        int base = cls*512 + pos;
        float img = (float)(*img_sz);
        float t = (float)label * (img + 2.0f);
        float o0 = b0+t, o1 = b1+t, o2 = b2+t, o3 = b3+t;
        ccs[base] = s;
        ccob[base] = make_float4(o0, o1, o2, o3);
        ccar[base] = fmaxf(o2-o0, 0.f) * fmaxf(o3-o1, 0.f);
        ccbx[base] = make_float4(b0, b1, b2, b3);
        ccix[base] = rem;   // reference flat order for tie-break
    }
}

// one wave per (image,class): greedy NMS entirely in registers
__global__ __launch_bounds__(64) void class_nms(
    const int* __restrict__ ccnt, const float* __restrict__ ccs,
    const float4* __restrict__ ccob, const float* __restrict__ ccar,
    const float4* __restrict__ ccbx, const int* __restrict__ ccix,
    float* __restrict__ svs, float4* __restrict__ svb, int* __restrict__ svi,
    int* __restrict__ svc)
{
    int cls = blockIdx.x;          // 0..159
    int Nc = ccnt[cls];
    int base = cls*512;
    int lane = threadIdx.x;
    __shared__ float sel[5];
    float s[8]; float4 ob[8]; float a[8]; int ix[8];
    int cntl = 0;
    for (int j = lane; j < Nc; j += 64) {
        s[cntl] = ccs[base+j]; ob[cntl] = ccob[base+j];
        a[cntl] = ccar[base+j]; ix[cntl] = ccix[base+j];
        ++cntl;
    }
    int svn = 0;
    int rounds = (Nc < 100) ? Nc : 100;
    for (int it = 0; it < rounds; ++it) {
        float bs = -1.f; int bi = 0x7fffffff;
        for (int q = 0; q < cntl; ++q)
            if (s[q] > bs || (s[q] == bs && ix[q] < bi)) { bs = s[q]; bi = ix[q]; }
        for (int off = 32; off > 0; off >>= 1) {
            float os = __shfl_xor(bs, off);
            int oi = __shfl_xor(bi, off);
            if (os > bs || (os == bs && oi < bi)) { bs = os; bi = oi; }
        }
        if (bs <= 0.f) break;      // uniform across wave
        for (int q = 0; q < cntl; ++q) {
            if (s[q] == bs && ix[q] == bi) {   // unique owner (ix unique)
                sel[0] = ob[q].x; sel[1] = ob[q].y; sel[2] = ob[q].z; sel[3] = ob[q].w;
                sel[4] = a[q];
                int slot = cls*128 + svn;
                svs[slot] = bs;
                svb[slot] = ccbx[base + lane + q*64];
                svi[slot] = bi;
                s[q] = -1.f;
            }
        }
        __syncthreads();
        float bi0 = sel[0], bi1 = sel[1], bi2 = sel[2], bi3 = sel[3], ai = sel[4];
        for (int q = 0; q < cntl; ++q) {
            if (s[q] > 0.f) {
                float ix1 = fmaxf(bi0, ob[q].x), iy1 = fmaxf(bi1, ob[q].y);
                float ix2 = fminf(bi2, ob[q].z), iy2 = fminf(bi3, ob[q].w);
                float inter = fmaxf(ix2-ix1, 0.f) * fmaxf(iy2-iy1, 0.f);
                float iou = inter / (ai + a[q] - inter + 1e-9f);
                if (iou > 0.5f) s[q] = -1.f;
            }
        }
        ++svn;
        __syncthreads();
    }
    if (lane == 0) svc[cls] = svn;
}

// per image: bitonic-sort survivors by (score desc, coidx asc), write top-100.
__global__ __launch_bounds__(256) void merge_topk(
    const float* __restrict__ svs, const float4* __restrict__ svb,
    const int* __restrict__ svi, const int* __restrict__ svc,
    float* __restrict__ out)
{
    extern __shared__ char smem[];
    u64* keys = (u64*)smem;                 // [8192] 64KB
    u32* pay  = (u32*)(smem + 65536);       // [8192] 32KB
    __shared__ int off[81];
    __shared__ int n2s;
    int b = blockIdx.x, tid = threadIdx.x;
    if (tid == 0) {
        int run = 0;
        for (int c = 0; c < 80; ++c) { off[c] = run; run += svc[b*80 + c]; }
        off[80] = run;
        int n2 = 256;
        while (n2 < run) n2 <<= 1;
        n2s = n2;
    }
    __syncthreads();
    int Ns = off[80], n2 = n2s;
    for (int c = 0; c < 80; ++c) {
        int n = off[c+1] - off[c];
        int srcb = (b*80 + c)*128;
        for (int k = tid; k < n; k += 256) {
            int src = srcb + k;
            keys[off[c] + k] = ((u64)__float_as_uint(svs[src]) << 32)
                             | (u64)(0xFFFFFFFFu - (u32)svi[src]);
            pay[off[c] + k] = src;
        }
    }
    for (int i = Ns + tid; i < n2; i += 256) { keys[i] = 0; pay[i] = 0; }
    __syncthreads();
    for (int k = 2; k <= n2; k <<= 1) {
        for (int j = k >> 1; j > 0; j >>= 1) {
            for (int i = tid; i < n2; i += 256) {
                int l = i ^ j;
                if (l > i) {
                    u64 a = keys[i], bb = keys[l];
                    bool dir = ((i & k) == 0);
                    if ((a < bb) == dir) {
                        keys[i] = bb; keys[l] = a;
                        u32 p = pay[i]; pay[i] = pay[l]; pay[l] = p;
                    }
                }
            }
            __syncthreads();
        }
    }
    if (tid < 100) {
        u64 kk = keys[tid];      // n2 >= 256 > 100 always
        if (kk != 0) {
            u32 ci = 0xFFFFFFFFu - (u32)(kk & 0xFFFFFFFFull);
            float4 bx = svb[pay[tid]];
            out[b*400 + tid*4 + 0] = bx.x;
            out[b*400 + tid*4 + 1] = bx.y;
            out[b*400 + tid*4 + 2] = bx.z;
            out[b*400 + tid*4 + 3] = bx.w;
            out[800  + b*100 + tid] = __uint_as_float((u32)(kk >> 32));
            out[1000 + b*100 + tid] = (float)((ci % 80) + 1);
        } else {
            out[b*400 + tid*4 + 0] = 0.f; out[b*400 + tid*4 + 1] = 0.f;
            out[b*400 + tid*4 + 2] = 0.f; out[b*400 + tid*4 + 3] = 0.f;
            out[800  + b*100 + tid] = 0.f;
            out[1000 + b*100 + tid] = 0.f;
        }
    }
}

extern "C" void kernel_launch(void* const* d_in, const int* in_sizes, int n_in,
                              void* d_out, int out_size, void* d_ws, size_t ws_size,
                              hipStream_t stream)
{
    const float* features  = (const float*)d_in[0];
    const float* proposals = (const float*)d_in[1];
    const float* fc1_w = (const float*)d_in[2];
    const float* fc1_b = (const float*)d_in[3];
    const float* fc2_w = (const float*)d_in[4];
    const float* fc2_b = (const float*)d_in[5];
    const float* cls_w = (const float*)d_in[6];
    const float* cls_b = (const float*)d_in[7];
    const float* bbox_w = (const float*)d_in[8];
    const float* bbox_b = (const float*)d_in[9];
    const int* img_sz = (const int*)d_in[10];
    float* out = (float*)d_out;
    char* ws = (char*)d_ws;
    _Float16* xhi   = (_Float16*)(ws + XHI_OFF);
    _Float16* xlo   = (_Float16*)(ws + XLO_OFF);
    _Float16* wt1hi = (_Float16*)(ws + WT1HI_OFF);
    _Float16* wt1lo = (_Float16*)(ws + WT1LO_OFF);
    _Float16* wt2hi = (_Float16*)(ws + WT2HI_OFF);
    _Float16* wt2lo = (_Float16*)(ws + WT2LO_OFF);
    _Float16* h1hi  = (_Float16*)(ws + H1HI_OFF);
    _Float16* h1lo  = (_Float16*)(ws + H1LO_OFF);
    float*  h2     = (float*) (ws + H2_OFF);
    float*  cwT    = (float*) (ws + CWT_OFF);
    float*  bwT    = (float*) (ws + BWT_OFF);
    float*  probs  = (float*) (ws + PROBS_OFF);
    float*  cur    = (float*) (ws + CUR_OFF);
    int*    ccnt   = (int*)   (ws + CNT_OFF);
    float*  ccs    = (float*) (ws + CCS_OFF);
    float4* ccob   = (float4*)(ws + CCOB_OFF);
    float*  ccar   = (float*) (ws + CCAR_OFF);
    float4* ccbx   = (float4*)(ws + CCBX_OFF);
    int*    ccix   = (int*)   (ws + CCIX_OFF);
    float*  svs    = (float*) (ws + SVS_OFF);
    float4* svb    = (float4*)(ws + SVB_OFF);
    int*    svi    = (int*)   (ws + SVI_OFF);
    int*    svc    = (int*)   (ws + SVC_OFF);
    float*  part   = (float*) (ws + PART_OFF);

    prep_kernel<<<1020, 256, 0, stream>>>(cls_w, bbox_w, cwT, bwT, ccnt);
    hipMemcpyAsync(cur, proposals, (size_t)NROWS*4*sizeof(float),
                   hipMemcpyDeviceToDevice, stream);

    for (int st = 0; st < 3; ++st) {
        // roi_align (chunk-parallel) || fc1-weight limb transpose
        roi_tl1_kernel<<<256*NCHUNK + 12544, 256, 0, stream>>>(
            features, cur, xhi, xlo,
            fc1_w + (size_t)st*INDIM*HID, wt1hi, wt1lo);
        // fc1: 392 K-steps; z=16 (8 x 25 + 8 x 24); 256 blocks = 1/CU
        mfma_gemm_limb256<<<256, 512, 131072, stream>>>(
            xhi, xlo, wt1hi, wt1lo, part, 24, 8);
        // reduce fc1 partials -> h1 limbs || fc2-weight limb transpose
        red1_tl2_kernel<<<4096 + 1024, 256, 0, stream>>>(
            part, fc1_b + st*HID, h1hi, h1lo,
            fc2_w + (size_t)st*HID*HID, wt2hi, wt2lo);
        // fc2: K=1024 = 32 K-steps; z=8 x 4 steps
        mfma_gemm_limb<<<512, 256, 0, stream>>>(
            h1hi, h1lo, wt2hi, wt2lo, part, 4, 0, 3);
        reduce_bias_relu<<<4096, 256, 0, stream>>>(
            part, fc2_b + st*HID, h2, 8);
        heads_kernel<<<NROWS/4, 512, 0, stream>>>(
            h2, cwT + (size_t)st*NCLS*HID, cls_b + st*NCLS,
            bwT + (size_t)st*4*HID, bbox_b + st*4,
            cur, probs, img_sz, st, st == 2 ? 1 : 0);
    }
    compact_class<<<(NB*CAND_PER_IMG)/256, 256, 0, stream>>>(
        probs, cur, img_sz, ccnt, ccs, ccob, ccar, ccbx, ccix);
    class_nms<<<160, 64, 0, stream>>>(
        ccnt, ccs, ccob, ccar, ccbx, ccix, svs, svb, svi, svc);
    merge_topk<<<NB, 256, 98304, stream>>>(
        svs, svb, svi, svc, out);
}